// Round 10
// baseline (351.961 us; speedup 1.0000x reference)
//
#include <hip/hip_runtime.h>
#include <math.h>

// VQVAE graph-transformer forward, fp32 throughout.
// B=4 N=128 DIM=256 HEADS=8 DH=64 EDGE=64 DEPTH=2 K=512 INNER=512
// R18 = R17 (319us ~ R13-equivalent) with attn rebuilt for occupancy:
// block per (b,h,i-DUO) (grid 1024->2048, 128 thr), each wave owns one
// query row (64 lanes x 2 j, float2 loads, full-wave softmax). LDS 24.7
// -> 20.7 KB. Waves/CU 8 -> ~14 (latency-bound L2 streaming loops).
// prep keeps R17's bias-fold-as-GEMM-row (absmax-identical). 14 dispatches.

#define DEV __device__ __forceinline__

constexpr int Bn = 4, Nn = 128, DIMn = 256, HEADSn = 8, DHn = 64, EDGEn = 64,
              DEPTHn = 2, Kn = 512, INNERn = 512;
constexpr int QKVW = 1536;
constexpr int PART = 131072;  // stride of partial buffers (floats)

DEV float wave_reduce_sum(float v) {
#pragma unroll
  for (int m = 32; m >= 1; m >>= 1) v += __shfl_xor(v, m);
  return v;
}

DEV float block_reduce_sum_256(float v, float* red) {
  v = wave_reduce_sum(v);
  int tid = threadIdx.x;
  if ((tid & 63) == 0) red[tid >> 6] = v;
  __syncthreads();
  v = red[0] + red[1] + red[2] + red[3];
  __syncthreads();
  return v;
}

DEV float gelu_exact(float x) {
  return 0.5f * x * (1.f + erff(x * 0.70710678118654752f));
}

// ---------------------------------------------------------------------------
// prep_kernel: all one-shot setup, block-range dispatched. 256 threads.
//  blk 0..431   : qkv weight+bias fold (216/layer: by 0..7 = W rows,
//                 by==8 = b_exp pseudo-row) 32x64 tiles, K=512, reg-dbuf
//  blk 432..943 : edge LN (b,i): 256 threads, vals[32]/thread
//  blk 944..1007: wfold W2 tile (l,h,nt), d-tiled 2x32
//  blk 1008..1015: wfold b_out2 (l,nt)
//  blk 1016..1031: rope tables
//  blk 1032..1543: LN0 row (xln + nodes copy)
__global__ __launch_bounds__(256) void prep_kernel(
    const float* __restrict__ edges, const float* __restrict__ eg,
    const float* __restrict__ eb, float* __restrict__ e,
    float* __restrict__ eT, float* __restrict__ cost, float* __restrict__ sint,
    const float* __restrict__ nodes_in, const float* __restrict__ ln1_g,
    const float* __restrict__ ln1_b, float* __restrict__ xln,
    float* __restrict__ nodes, const float* __restrict__ wek,
    const float* __restrict__ w_out, const float* __restrict__ bek,
    const float* __restrict__ b_out, float* __restrict__ W2,
    float* __restrict__ b_out2, const float* __restrict__ w_exp,
    const float* __restrict__ b_exp, const float* __restrict__ w_q,
    const float* __restrict__ b_q, const float* __restrict__ w_kv,
    const float* __restrict__ b_kv, float* __restrict__ WqkvF,
    float* __restrict__ bqkvF) {
  __shared__ __align__(16) float smem[4736];  // 18.9 KB, aliased per role
  int blk = blockIdx.x;
  int tid = threadIdx.x;

  if (blk < 432) {  // ---- qkv weight+bias fold: 32x64 tile, K=512, dbuf ----
    int t = blk;  // 0..431
    int l = t / 216, r = t % 216;
    int by = r / 24, bx = r % 24;
    bool biasrow = (by == 8);
    float* As = smem;            // [32][34]
    float* Bs = smem + 32 * 34;  // [32][68]
    int n0 = bx * 64;
    const float* Aab = w_exp + (size_t)l * 256 * 512 + (size_t)(by * 32) * 512;
    const float* be = b_exp + l * 512;
    const float* Wb;
    int ldw;
    if (n0 < 512) {
      Wb = w_q + (size_t)l * 512 * 512 + n0;
      ldw = 512;
    } else {
      Wb = w_kv + (size_t)l * 512 * 1024 + (n0 - 512);
      ldw = 1024;
    }
    int arow = tid >> 3, acol = (tid & 7) << 2;
    int brow = tid >> 4, bcol = (tid & 15) << 2;
    int tx = tid & 15, ty = tid >> 4;
    auto lda = [&](int kpos) -> float4 {
      return biasrow ? *(const float4*)(be + kpos + acol)
                     : *(const float4*)(Aab + (size_t)arow * 512 + kpos + acol);
    };
    float4 a_nxt = lda(0);
    float4 b0_nxt = *(const float4*)(Wb + (size_t)brow * ldw + bcol);
    float4 b1_nxt = *(const float4*)(Wb + (size_t)(brow + 16) * ldw + bcol);
    float acc[2][4] = {};
    for (int k0 = 0; k0 < 512; k0 += 32) {
      As[(acol + 0) * 34 + arow] = a_nxt.x;
      As[(acol + 1) * 34 + arow] = a_nxt.y;
      As[(acol + 2) * 34 + arow] = a_nxt.z;
      As[(acol + 3) * 34 + arow] = a_nxt.w;
      *(float4*)&Bs[brow * 68 + bcol] = b0_nxt;
      *(float4*)&Bs[(brow + 16) * 68 + bcol] = b1_nxt;
      __syncthreads();
      int kn = k0 + 32;
      if (kn < 512) {
        a_nxt = lda(kn);
        b0_nxt = *(const float4*)(Wb + (size_t)(kn + brow) * ldw + bcol);
        b1_nxt = *(const float4*)(Wb + (size_t)(kn + brow + 16) * ldw + bcol);
      }
#pragma unroll
      for (int kk = 0; kk < 32; ++kk) {
        float2 av = *(const float2*)&As[kk * 34 + ty * 2];
        float4 bv = *(const float4*)&Bs[kk * 68 + tx * 4];
        acc[0][0] += av.x * bv.x;
        acc[0][1] += av.x * bv.y;
        acc[0][2] += av.x * bv.z;
        acc[0][3] += av.x * bv.w;
        acc[1][0] += av.y * bv.x;
        acc[1][1] += av.y * bv.y;
        acc[1][2] += av.y * bv.z;
        acc[1][3] += av.y * bv.w;
      }
      __syncthreads();
    }
    if (!biasrow) {
#pragma unroll
      for (int u = 0; u < 2; ++u) {
        int d = by * 32 + ty * 2 + u;
        float4 o = {acc[u][0], acc[u][1], acc[u][2], acc[u][3]};
        *(float4*)(WqkvF + (size_t)l * 256 * 1536 + (size_t)d * 1536 + n0 +
                   tx * 4) = o;
      }
    } else if (ty == 0) {
      // pseudo-row d==0 (u==0) holds the b_exp dot; add base q/kv bias.
#pragma unroll
      for (int w = 0; w < 4; ++w) {
        int n = n0 + tx * 4 + w;
        float bb = (n < 512) ? b_q[l * 512 + n] : b_kv[l * 1024 + (n - 512)];
        bqkvF[l * 1536 + n] = acc[0][w] + bb;
      }
    }
  } else if (blk < 944) {  // ---- edge LN: 256 threads, no spill ----
    float* ets = smem;          // [128][33] = 4224
    float* redS = smem + 4224;  // 256
    float* redQ = smem + 4480;  // 256
    int eidx = blk - 432;
    int i = eidx & 127, b = eidx >> 7;
    int j = tid & 127, half = tid >> 7;
    const float* src = edges + (size_t)b * EDGEn * Nn * Nn +
                       (size_t)(half * 32) * (Nn * Nn) + i * Nn + j;
    float vals[32];
    float s = 0.f, q = 0.f;
#pragma unroll
    for (int cc = 0; cc < 32; ++cc) {
      float x = src[(size_t)cc * (Nn * Nn)];
      vals[cc] = x;
      s += x;
      q += x * x;
    }
    redS[tid] = s;
    redQ[tid] = q;
    __syncthreads();
    float ts = redS[j] + redS[j + 128];
    float tq = redQ[j] + redQ[j + 128];
    float m = ts * (1.0f / 64.0f);
    float var = tq * (1.0f / 64.0f) - m * m;
    float inv = 1.f / sqrtf(var + 1e-5f);
    float* dst = e + ((size_t)(b * Nn + i) * EDGEn) * Nn + j;
#pragma unroll
    for (int cc = 0; cc < 32; ++cc) {
      int c = half * 32 + cc;
      float o = (vals[cc] - m) * inv * eg[c] + eb[c];
      vals[cc] = o;
      dst[(size_t)c * Nn] = o;
    }
    float* dstT = eT + ((size_t)(b * Nn + i) * Nn) * EDGEn;
#pragma unroll
    for (int ch = 0; ch < 2; ++ch) {
      __syncthreads();  // guard ets reuse (and redS/redQ reads on pass 0)
      if (half == ch) {
#pragma unroll
        for (int cc = 0; cc < 32; ++cc) ets[j * 33 + cc] = vals[cc];
      }
      __syncthreads();
#pragma unroll
      for (int it = 0; it < 4; ++it) {
        int f4 = it * 256 + tid;  // 1024 float4s: 128 j x 8 c4
        int jj = f4 >> 3, c4 = (f4 & 7) << 2;
        float4 o4 = {ets[jj * 33 + c4], ets[jj * 33 + c4 + 1],
                     ets[jj * 33 + c4 + 2], ets[jj * 33 + c4 + 3]};
        *(float4*)(dstT + (size_t)jj * EDGEn + ch * 32 + c4) = o4;
      }
    }
  } else if (blk < 1008) {  // ---- wfold W2, d-tiled 2x32 ----
    int t = blk - 944;
    int l = t >> 5, h = (t >> 2) & 7, nt = t & 3;
    float* As = smem;            // [64][36] = 2304
    float* Bs = smem + 2304;     // [32][68] = 2176
    const float* wekl = wek + (size_t)l * 64 * 512 + h * 64;
    const float* woutl =
        w_out + (size_t)l * 512 * 256 + (size_t)(h * 64) * 256 + nt * 64;
    int tx = tid & 15, ty = tid >> 4;
    float acc[4][4] = {};
    for (int d0 = 0; d0 < 64; d0 += 32) {
      for (int f = tid; f < 512; f += 256) {
        int c = f >> 3, d4 = (f & 7) << 2;
        *(float4*)&As[c * 36 + d4] =
            *(const float4*)(wekl + (size_t)c * 512 + d0 + d4);
      }
      for (int f = tid; f < 512; f += 256) {
        int dd = f >> 4, n4 = (f & 15) << 2;
        *(float4*)&Bs[dd * 68 + n4] =
            *(const float4*)(woutl + (size_t)(d0 + dd) * 256 + n4);
      }
      __syncthreads();
#pragma unroll
      for (int dd = 0; dd < 32; ++dd) {
        float4 bv = *(const float4*)&Bs[dd * 68 + tx * 4];
#pragma unroll
        for (int u = 0; u < 4; ++u) {
          float a = As[(ty * 4 + u) * 36 + dd];
          acc[u][0] += a * bv.x;
          acc[u][1] += a * bv.y;
          acc[u][2] += a * bv.z;
          acc[u][3] += a * bv.w;
        }
      }
      __syncthreads();
    }
#pragma unroll
    for (int u = 0; u < 4; ++u) {
      float4 o = {acc[u][0], acc[u][1], acc[u][2], acc[u][3]};
      *(float4*)(W2 + (size_t)l * 512 * 256 +
                 (size_t)(h * 64 + ty * 4 + u) * 256 + nt * 64 + tx * 4) = o;
    }
  } else if (blk < 1016) {  // ---- wfold b_out2 ----
    int t = blk - 1008;
    int l = t >> 2, nt = t & 3;
    float* part = smem;
    int nn = tid & 63, kq = tid >> 6;
    const float* wcol = w_out + (size_t)l * 512 * 256 + nt * 64 + nn;
    float acc = 0.f;
    for (int k = kq * 128; k < kq * 128 + 128; ++k)
      acc += bek[l * 512 + k] * wcol[(size_t)k * 256];
    part[tid] = acc;
    __syncthreads();
    if (tid < 64)
      b_out2[l * 256 + nt * 64 + nn] =
          b_out[l * 256 + nt * 64 + nn] + part[nn] + part[64 + nn] +
          part[128 + nn] + part[192 + nn];
  } else if (blk < 1032) {  // ---- rope tables ----
    int t = (blk - 1016) * 256 + tid;
    if (t < Nn * 32) {
      int n = t >> 5, p = t & 31;
      float inv = powf(10000.f, -(float)(2 * p) / 64.f);
      float fr = (float)n * inv;
      cost[t] = cosf(fr);
      sint[t] = sinf(fr);
    }
  } else {  // ---- LN0 + nodes copy ----
    float* red = smem;
    int row = blk - 1032;
    float v = nodes_in[(size_t)row * DIMn + tid];
    nodes[(size_t)row * DIMn + tid] = v;
    float m = block_reduce_sum_256(v, red) * (1.0f / 256.0f);
    float d = v - m;
    float var = block_reduce_sum_256(d * d, red) * (1.0f / 256.0f);
    float inv = 1.f / sqrtf(var + 1e-5f);
    xln[(size_t)row * DIMn + tid] = d * inv * ln1_g[tid] + ln1_b[tid];
  }
}

// ---------------------------------------------------------------------------
// fp32 GEMM, 32x64 tile, BK=32, 2x4 microtile, register double-buffered.
// A2: A-stage sums two partials; aact==1: gelu after the sum.
// Dual-N (W2n at col>=N1), dual-K (k>=Ksplit reads Wkb), split-K via z.
// act: 0 none, 1 exact gelu, 4 qkv mode (rope cols<1024; k section -> kT).
__global__ __launch_bounds__(256) void gemm_kernel(
    const float* __restrict__ A, const float* __restrict__ A2, int aact,
    const float* __restrict__ W1, int N1, const float* __restrict__ b1,
    const float* __restrict__ W2n, int N2, const float* __restrict__ b2,
    const float* __restrict__ Wkb, int Ksplit, float* __restrict__ C, int M,
    int Ntot, int K, int kspan, int act, const float* __restrict__ cost,
    const float* __restrict__ sint, float* __restrict__ kT) {
  __shared__ float As[32][34];
  __shared__ __align__(16) float Bs[32][68];
  int tid = threadIdx.x;
  int bx = blockIdx.x, by = blockIdx.y, zid = blockIdx.z;
  int tx = tid & 15, ty = tid >> 4;
  int arow = tid >> 3, acol = (tid & 7) << 2;
  int brow = tid >> 4, bcol = (tid & 15) << 2;
  int col0 = bx * 64;
  const float* W = W1;
  const float* bias = b1;
  int Nw = N1, wcol = col0;
  if (W2n && col0 >= N1) {
    W = W2n;
    bias = b2;
    Nw = N2;
    wcol = col0 - N1;
  }
  int kb = zid * kspan, kend = kb + kspan;
  const float* arp = A + (size_t)(by * 32 + arow) * K;
  const float* arp2 = A2 ? A2 + (size_t)(by * 32 + arow) * K : nullptr;

  auto load_a = [&](int kpos) -> float4 {
    float4 a = *(const float4*)(arp + kpos + acol);
    if (arp2) {
      float4 a2 = *(const float4*)(arp2 + kpos + acol);
      a.x += a2.x;
      a.y += a2.y;
      a.z += a2.z;
      a.w += a2.w;
    }
    if (aact == 1) {
      a.x = gelu_exact(a.x);
      a.y = gelu_exact(a.y);
      a.z = gelu_exact(a.z);
      a.w = gelu_exact(a.w);
    }
    return a;
  };

  float4 a_nxt = load_a(kb);
  const float* w0p;
  const float* w1p;
  {
    int kr0 = kb + brow, kr1 = kb + brow + 16;
    w0p = (Ksplit && kr0 >= Ksplit)
              ? Wkb + (size_t)(kr0 - Ksplit) * Nw + wcol + bcol
              : W + (size_t)kr0 * Nw + wcol + bcol;
    w1p = (Ksplit && kr1 >= Ksplit)
              ? Wkb + (size_t)(kr1 - Ksplit) * Nw + wcol + bcol
              : W + (size_t)kr1 * Nw + wcol + bcol;
  }
  float4 b0_nxt = *(const float4*)w0p;
  float4 b1_nxt = *(const float4*)w1p;

  float acc[2][4] = {};
  for (int k0 = kb; k0 < kend; k0 += 32) {
    As[acol + 0][arow] = a_nxt.x;
    As[acol + 1][arow] = a_nxt.y;
    As[acol + 2][arow] = a_nxt.z;
    As[acol + 3][arow] = a_nxt.w;
    *(float4*)&Bs[brow][bcol] = b0_nxt;
    *(float4*)&Bs[brow + 16][bcol] = b1_nxt;
    __syncthreads();
    int kn = k0 + 32;
    if (kn < kend) {
      a_nxt = load_a(kn);
      int kr0 = kn + brow, kr1 = kn + brow + 16;
      w0p = (Ksplit && kr0 >= Ksplit)
                ? Wkb + (size_t)(kr0 - Ksplit) * Nw + wcol + bcol
                : W + (size_t)kr0 * Nw + wcol + bcol;
      w1p = (Ksplit && kr1 >= Ksplit)
                ? Wkb + (size_t)(kr1 - Ksplit) * Nw + wcol + bcol
                : W + (size_t)kr1 * Nw + wcol + bcol;
      b0_nxt = *(const float4*)w0p;
      b1_nxt = *(const float4*)w1p;
    }
#pragma unroll
    for (int kk = 0; kk < 32; ++kk) {
      float2 av = *(const float2*)&As[kk][ty * 2];
      float4 bv = *(const float4*)&Bs[kk][tx * 4];
      acc[0][0] += av.x * bv.x;
      acc[0][1] += av.x * bv.y;
      acc[0][2] += av.x * bv.z;
      acc[0][3] += av.x * bv.w;
      acc[1][0] += av.y * bv.x;
      acc[1][1] += av.y * bv.y;
      acc[1][2] += av.y * bv.z;
      acc[1][3] += av.y * bv.w;
    }
    __syncthreads();
  }
  int ccol = wcol + tx * 4;
  bool ksec = (act == 4) && (col0 >= 512) && (col0 < 1024);
  float* trans = (float*)Bs;
  float* Cz = C + (size_t)zid * M * Ntot;
#pragma unroll
  for (int u = 0; u < 2; ++u) {
    int r = by * 32 + ty * 2 + u;
    float o[4];
#pragma unroll
    for (int w = 0; w < 4; ++w)
      o[w] = acc[u][w] + (zid == 0 ? bias[ccol + w] : 0.f);
    if (act == 1) {
#pragma unroll
      for (int w = 0; w < 4; ++w) o[w] = gelu_exact(o[w]);
    } else if (act == 4 && col0 < 1024) {
      int n = r & 127;
      int p0 = (ccol & 63) >> 1;
      float c0 = cost[n * 32 + p0], s0 = sint[n * 32 + p0];
      float c1 = cost[n * 32 + p0 + 1], s1 = sint[n * 32 + p0 + 1];
      float x0 = o[0], x1 = o[1], x2 = o[2], x3 = o[3];
      o[0] = x0 * c0 - x1 * s0;
      o[1] = x1 * c0 + x0 * s0;
      o[2] = x2 * c1 - x3 * s1;
      o[3] = x3 * c1 + x2 * s1;
    }
    if (ksec) {
#pragma unroll
      for (int w = 0; w < 4; ++w) trans[(tx * 4 + w) * 33 + ty * 2 + u] = o[w];
    } else {
      float4 o4 = {o[0], o[1], o[2], o[3]};
      *(float4*)(Cz + (size_t)r * Ntot + col0 + tx * 4) = o4;
    }
  }
  if (ksec) {
    __syncthreads();
    int h = (col0 - 512) >> 6;
    int bb = (by * 32) >> 7;
#pragma unroll
    for (int q = 0; q < 2; ++q) {
      int f4 = tid * 2 + q;
      int dl = f4 >> 3, j4 = (f4 & 7) << 2;
      int jj = (by * 32 + j4) & 127;
      float4 o4 = {trans[dl * 33 + j4], trans[dl * 33 + j4 + 1],
                   trans[dl * 33 + j4 + 2], trans[dl * 33 + j4 + 3]};
      *(float4*)(kT + ((size_t)(bb * 8 + h) * 64 + dl) * 128 + jj) = o4;
    }
  }
}

// ---------------------------------------------------------------------------
// Attention + qe + out-proj partial. Block per (b,h,i-DUO), 128 threads.
// Each wave owns one query row (64 lanes x 2 j each; full-wave softmax).
// Writes per-head proj partial: proj[h*PART + row*256 + n].
__global__ __launch_bounds__(128) void attn_kernel(
    const float* __restrict__ qkv, const float* __restrict__ e,
    const float* __restrict__ eT, const float* __restrict__ kT,
    const float* __restrict__ wek, const float* __restrict__ w_out,
    const float* __restrict__ W2, float* __restrict__ proj) {
  __shared__ __align__(16) float qs[128];
  __shared__ __align__(16) float qes[128];
  __shared__ __align__(16) float att[256];
  __shared__ float avh[256];
  __shared__ float aeh[256];
  __shared__ float wekh[64 * 65];
  int blk = blockIdx.x;
  int iq = blk & 63;  // 64 i-duos
  int bh = blk >> 6;
  int h = bh & 7, b = bh >> 3;
  int i0 = iq * 2;
  int row0 = b * 128 + i0;
  int tid = threadIdx.x;

  {
    int ii = tid >> 6, d = tid & 63;
    qs[tid] = qkv[(size_t)(row0 + ii) * QKVW + h * 64 + d];
  }
  for (int f = tid; f < 4096; f += 128) {
    int c = f >> 6, d = f & 63;
    wekh[c * 65 + d] = wek[(size_t)c * INNERn + h * 64 + d];
  }
  __syncthreads();

  {
    int ii = tid >> 6, c = tid & 63;
    float acc = 0.f;
#pragma unroll
    for (int d = 0; d < 64; ++d) acc += qs[ii * 64 + d] * wekh[c * 65 + d];
    qes[tid] = acc;
  }
  __syncthreads();

  int i2 = tid >> 6, j2 = tid & 63;  // wave i2 = row i2; lane j2 owns 2 j's
  float s0 = 0.f, s1 = 0.f;
  {
    const float* ktb = kT + (size_t)bh * 8192 + j2 * 2;
#pragma unroll
    for (int d4 = 0; d4 < 64; d4 += 4) {
      float4 q4 = *(const float4*)&qs[i2 * 64 + d4];
      float2 k0 = *(const float2*)(ktb + (size_t)(d4 + 0) * 128);
      float2 k1 = *(const float2*)(ktb + (size_t)(d4 + 1) * 128);
      float2 k2 = *(const float2*)(ktb + (size_t)(d4 + 2) * 128);
      float2 k3 = *(const float2*)(ktb + (size_t)(d4 + 3) * 128);
      s0 += q4.x * k0.x + q4.y * k1.x + q4.z * k2.x + q4.w * k3.x;
      s1 += q4.x * k0.y + q4.y * k1.y + q4.z * k2.y + q4.w * k3.y;
    }
    const float* eb = e + (size_t)(row0 + i2) * 8192 + j2 * 2;
#pragma unroll
    for (int c4 = 0; c4 < 64; c4 += 4) {
      float4 qe4 = *(const float4*)&qes[i2 * 64 + c4];
      float2 e0 = *(const float2*)(eb + (size_t)(c4 + 0) * 128);
      float2 e1 = *(const float2*)(eb + (size_t)(c4 + 1) * 128);
      float2 e2 = *(const float2*)(eb + (size_t)(c4 + 2) * 128);
      float2 e3 = *(const float2*)(eb + (size_t)(c4 + 3) * 128);
      s0 += qe4.x * e0.x + qe4.y * e1.x + qe4.z * e2.x + qe4.w * e3.x;
      s1 += qe4.x * e0.y + qe4.y * e1.y + qe4.z * e2.y + qe4.w * e3.y;
    }
    s0 *= 0.125f;
    s1 *= 0.125f;
  }
  {
    float mx = fmaxf(s0, s1);
#pragma unroll
    for (int m = 32; m >= 1; m >>= 1) mx = fmaxf(mx, __shfl_xor(mx, m));
    float p0 = expf(s0 - mx), p1 = expf(s1 - mx);
    float sm = p0 + p1;
#pragma unroll
    for (int m = 32; m >= 1; m >>= 1) sm += __shfl_xor(sm, m);
    float inv = 1.f / sm;
    float2 a2 = {p0 * inv, p1 * inv};
    *(float2*)&att[i2 * 128 + j2 * 2] = a2;
  }
  __syncthreads();

  {
    int d = tid & 63, half = tid >> 6;
    float av0 = 0.f, av1 = 0.f;
    float ae0 = 0.f, ae1 = 0.f;
    const float* vb = qkv + (size_t)(b * 128) * QKVW + 1024 + h * 64 + d;
    const float* etb = eT + ((size_t)row0 * 128) * 64 + d;
    for (int jq = 0; jq < 16; ++jq) {
      int jb = half * 64 + jq * 4;
      float4 a0 = *(const float4*)&att[0 * 128 + jb];
      float4 a1 = *(const float4*)&att[1 * 128 + jb];
#pragma unroll
      for (int t = 0; t < 4; ++t) {
        int j = jb + t;
        float vv = vb[(size_t)j * QKVW];
        float at0 = ((const float*)&a0)[t];
        float at1 = ((const float*)&a1)[t];
        av0 += at0 * vv;
        av1 += at1 * vv;
        float e0 = etb[(size_t)j * 64];
        float e1 = etb[8192 + (size_t)j * 64];
        ae0 += at0 * e0;
        ae1 += at1 * e1;
      }
    }
    avh[half * 128 + 0 * 64 + d] = av0;
    avh[half * 128 + 1 * 64 + d] = av1;
    aeh[half * 128 + 0 * 64 + d] = ae0;
    aeh[half * 128 + 1 * 64 + d] = ae1;
  }
  __syncthreads();

  {
    int ii = tid >> 6, dd = tid & 63;
    att[ii * 128 + dd] = avh[ii * 64 + dd] + avh[128 + ii * 64 + dd];
    att[ii * 128 + 64 + dd] = aeh[ii * 64 + dd] + aeh[128 + ii * 64 + dd];
  }
  __syncthreads();

  {
    int rp = tid >> 6, n4 = (tid & 63) << 2;
    float o0[4] = {};
    const float* wo = w_out + (size_t)(h * 64) * 256 + n4;
#pragma unroll 8
    for (int k = 0; k < 64; ++k) {
      float4 w4 = *(const float4*)(wo + (size_t)k * 256);
      float a0 = att[rp * 128 + k];
      o0[0] += a0 * w4.x;
      o0[1] += a0 * w4.y;
      o0[2] += a0 * w4.z;
      o0[3] += a0 * w4.w;
    }
    const float* w2 = W2 + (size_t)(h * 64) * 256 + n4;
#pragma unroll 8
    for (int k = 0; k < 64; ++k) {
      float4 w4 = *(const float4*)(w2 + (size_t)k * 256);
      float a0 = att[rp * 128 + 64 + k];
      o0[0] += a0 * w4.x;
      o0[1] += a0 * w4.y;
      o0[2] += a0 * w4.z;
      o0[3] += a0 * w4.w;
    }
    float* pp = proj + (size_t)h * PART;
    float4 v0 = {o0[0], o0[1], o0[2], o0[3]};
    *(float4*)(pp + (size_t)(row0 + rp) * 256 + n4) = v0;
  }
}

// ---------------------------------------------------------------------------
// Gated residual + optional fused LN. x = sum of nparts partials (+ badd).
__global__ __launch_bounds__(256) void gate_ln_kernel(
    const float* __restrict__ x, int nparts, const float* __restrict__ badd,
    float* __restrict__ nodes, const float* __restrict__ gw,
    const float* __restrict__ lng, const float* __restrict__ lnb,
    float* __restrict__ xln) {
  __shared__ float red[4];
  int row = blockIdx.x, tid = threadIdx.x;
  size_t off = (size_t)row * DIMn + tid;
  float xv = x[off];
  for (int p = 1; p < nparts; ++p) xv += x[off + (size_t)p * PART];
  if (badd) xv += badd[tid];
  float rv = nodes[off];
  float pv =
      xv * gw[tid] + rv * gw[DIMn + tid] + (xv - rv) * gw[2 * DIMn + tid];
  float ssum = block_reduce_sum_256(pv, red);
  float gsig = 1.f / (1.f + expf(-ssum));
  float nv = xv * gsig + rv * (1.f - gsig);
  nodes[off] = nv;
  if (lng) {
    float m = block_reduce_sum_256(nv, red) * (1.0f / 256.0f);
    float d = nv - m;
    float var = block_reduce_sum_256(d * d, red) * (1.0f / 256.0f);
    float inv = 1.f / sqrtf(var + 1e-5f);
    xln[off] = d * inv * lng[tid] + lnb[tid];
  }
}

// ---------------------------------------------------------------------------
// VQ nearest neighbor: thread-per-codebook-entry, 4 rows per block.
__global__ __launch_bounds__(256) void vq_kernel(
    const float* __restrict__ nodes, const float* __restrict__ codebook,
    float* __restrict__ out) {
  __shared__ __align__(16) float zs[4 * 256];
  __shared__ float wval[4][4];
  __shared__ int widx[4][4];
  __shared__ int fidx[4];
  int row0 = blockIdx.x * 4;
  int tid = threadIdx.x;
  for (int f = tid; f < 1024; f += 256) zs[f] = nodes[(size_t)row0 * DIMn + f];
  __syncthreads();
  int k1 = tid, k2 = tid + 256;
  const float4* c1p = (const float4*)(codebook + (size_t)k1 * DIMn);
  const float4* c2p = (const float4*)(codebook + (size_t)k2 * DIMn);
  float dot[4][2] = {};
  float cc0 = 0.f, cc1 = 0.f;
#pragma unroll 8
  for (int d4 = 0; d4 < 64; ++d4) {
    float4 c1 = c1p[d4], c2 = c2p[d4];
    cc0 += c1.x * c1.x + c1.y * c1.y + c1.z * c1.z + c1.w * c1.w;
    cc1 += c2.x * c2.x + c2.y * c2.y + c2.z * c2.z + c2.w * c2.w;
#pragma unroll
    for (int r = 0; r < 4; ++r) {
      float4 z = *(const float4*)&zs[r * 256 + d4 * 4];
      dot[r][0] += c1.x * z.x + c1.y * z.y + c1.z * z.z + c1.w * z.w;
      dot[r][1] += c2.x * z.x + c2.y * z.y + c2.z * z.z + c2.w * z.w;
    }
  }
  int lane = tid & 63, w = tid >> 6;
#pragma unroll
  for (int r = 0; r < 4; ++r) {
    float bv = cc0 - 2.f * dot[r][0];
    int bi = k1;
    float v2 = cc1 - 2.f * dot[r][1];
    if (v2 < bv) {
      bv = v2;
      bi = k2;
    }
#pragma unroll
    for (int m = 32; m >= 1; m >>= 1) {
      float ov = __shfl_xor(bv, m);
      int oi = __shfl_xor(bi, m);
      if (ov < bv || (ov == bv && oi < bi)) {
        bv = ov;
        bi = oi;
      }
    }
    if (lane == 0) {
      wval[r][w] = bv;
      widx[r][w] = bi;
    }
  }
  __syncthreads();
  if (tid < 4) {
    float bb = wval[tid][0];
    int bi = widx[tid][0];
    for (int t = 1; t < 4; ++t)
      if (wval[tid][t] < bb || (wval[tid][t] == bb && widx[tid][t] < bi)) {
        bb = wval[tid][t];
        bi = widx[tid][t];
      }
    fidx[tid] = bi;
  }
  __syncthreads();
  for (int f = tid; f < 1024; f += 256) {
    int r = f >> 8, d = f & 255;
    float zv = zs[f];
    float zq = codebook[(size_t)fidx[r] * DIMn + d];
    out[(size_t)(row0 + r) * DIMn + d] = zv + (zq - zv);
  }
}

// ---------------------------------------------------------------------------
extern "C" void kernel_launch(void* const* d_in, const int* in_sizes, int n_in,
                              void* d_out, int out_size, void* d_ws,
                              size_t ws_size, hipStream_t stream) {
  const float* nodes_in = (const float*)d_in[0];
  const float* edges = (const float*)d_in[1];
  const float* edge_ln_g = (const float*)d_in[2];
  const float* edge_ln_b = (const float*)d_in[3];
  const float* ln1_g = (const float*)d_in[4];
  const float* ln1_b = (const float*)d_in[5];
  const float* w_exp = (const float*)d_in[6];
  const float* b_exp = (const float*)d_in[7];
  const float* w_q = (const float*)d_in[8];
  const float* b_q = (const float*)d_in[9];
  const float* w_kv = (const float*)d_in[10];
  const float* b_kv = (const float*)d_in[11];
  const float* w_ekv = (const float*)d_in[12];
  const float* b_ekv = (const float*)d_in[13];
  const float* w_out = (const float*)d_in[14];
  const float* b_out = (const float*)d_in[15];
  const float* gate1_w = (const float*)d_in[16];
  const float* ln2_g = (const float*)d_in[17];
  const float* ln2_b = (const float*)d_in[18];
  const float* w_ff1 = (const float*)d_in[19];
  const float* b_ff1 = (const float*)d_in[20];
  const float* w_ff2 = (const float*)d_in[21];
  const float* b_ff2 = (const float*)d_in[22];
  const float* gate2_w = (const float*)d_in[23];
  const float* codebook = (const float*)d_in[24];

  float* ws = (float*)d_ws;
  float* e_buf = ws;                  // 4194304
  float* eT_buf = e_buf + 4194304;    // 4194304
  float* cost = eT_buf + 4194304;     // 4096
  float* sint = cost + 4096;          // 4096
  float* nodes = sint + 4096;         // 131072
  float* xln = nodes + 131072;        // 131072
  float* qkvb = xln + 131072;         // 786432
  float* kTb = qkvb + 786432;         // 262144
  float* proj = kTb + 262144;         // 1048576 (8 per-head / 4 splitK parts)
  float* ff1 = proj + 1048576;        // 1048576 (2 split-K partials)
  float* W2buf = ff1 + 1048576;       // 262144
  float* bout2 = W2buf + 262144;      // 512
  float* WqkvF = bout2 + 512;         // 786432 (2 layers x 256 x 1536)
  float* bqkvF = WqkvF + 786432;      // 3072

  // one-shot setup: fold (weight+bias) first, edge LN, W2, rope, LN0 fillers
  prep_kernel<<<1544, 256, 0, stream>>>(
      edges, edge_ln_g, edge_ln_b, e_buf, eT_buf, cost, sint, nodes_in, ln1_g,
      ln1_b, xln, nodes, w_ekv, w_out, b_ekv, b_out, W2buf, bout2, w_exp,
      b_exp, w_q, b_q, w_kv, b_kv, WqkvF, bqkvF);

  for (int l = 0; l < DEPTHn; ++l) {
    // fused q|kv directly from xln via folded weights (K=256), rope + kT
    gemm_kernel<<<dim3(24, 16, 1), 256, 0, stream>>>(
        xln, nullptr, 0, WqkvF + (size_t)l * 256 * 1536, 1536,
        bqkvF + l * 1536, nullptr, 0, nullptr, nullptr, 0, qkvb, 512, QKVW,
        256, 256, 4, cost, sint, kTb);
    // attention (+qe, +out-proj per-head partials), i-duo blocks
    attn_kernel<<<2048, 128, 0, stream>>>(qkvb, e_buf, eT_buf, kTb,
                                          w_ekv + l * 64 * 512,
                                          w_out + l * 512 * 256,
                                          W2buf + l * 512 * 256, proj);
    gate_ln_kernel<<<512, 256, 0, stream>>>(
        proj, 8, bout2 + l * 256, nodes, gate1_w + l * 768, ln2_g + l * 256,
        ln2_b + l * 256, xln);
    // ff1: split-K x2 (gelu deferred to ff2 A-stage)
    gemm_kernel<<<dim3(16, 16, 2), 256, 0, stream>>>(
        xln, nullptr, 0, w_ff1 + l * 256 * 1024, 1024, b_ff1 + l * 1024,
        nullptr, 0, nullptr, nullptr, 0, ff1, 512, 1024, 256, 128, 0, cost,
        sint, nullptr);
    // ff2: A = gelu(ff1 p0 + p1), split-K x4 -> proj partials
    gemm_kernel<<<dim3(4, 16, 4), 256, 0, stream>>>(
        ff1, ff1 + 524288, 1, w_ff2 + l * 1024 * 256, 256, b_ff2 + l * 256,
        nullptr, 0, nullptr, nullptr, 0, proj, 512, 256, 1024, 256, 0, cost,
        sint, nullptr);
    const float* nlng = (l + 1 < DEPTHn) ? ln1_g + (l + 1) * 256 : nullptr;
    const float* nlnb = (l + 1 < DEPTHn) ? ln1_b + (l + 1) * 256 : nullptr;
    gate_ln_kernel<<<512, 256, 0, stream>>>(proj, 4, nullptr, nodes,
                                            gate2_w + l * 768, nlng, nlnb,
                                            xln);
  }
  vq_kernel<<<128, 256, 0, stream>>>(nodes, codebook, (float*)d_out);
}

// Round 11
// 327.743 us; speedup vs baseline: 1.0739x; 1.0739x over previous
//
#include <hip/hip_runtime.h>
#include <math.h>

// VQVAE graph-transformer forward, fp32 throughout.
// B=4 N=128 DIM=256 HEADS=8 DH=64 EDGE=64 DEPTH=2 K=512 INNER=512
// R19 = R17 (319us) with attn processing 2 HEADS per block (grid 512, 128
// thr, i-quad unchanged): every e/eT element is loaded once per thread and
// used for both heads (the 2x134MB head-redundant re-reads were the largest
// L2 term; attn is traffic-bound per R18's failed occupancy experiment).
// wekh staged sequentially per head (LDS 33KB); out-proj keeps 2-row w4
// reuse per head (R18 lesson: fixed-cost/reuse dominates). Per-head math
// and reduction order identical to R13 -> absmax unchanged. 14 dispatches.

#define DEV __device__ __forceinline__

constexpr int Bn = 4, Nn = 128, DIMn = 256, HEADSn = 8, DHn = 64, EDGEn = 64,
              DEPTHn = 2, Kn = 512, INNERn = 512;
constexpr int QKVW = 1536;
constexpr int PART = 131072;  // stride of partial buffers (floats)

DEV float wave_reduce_sum(float v) {
#pragma unroll
  for (int m = 32; m >= 1; m >>= 1) v += __shfl_xor(v, m);
  return v;
}

DEV float block_reduce_sum_256(float v, float* red) {
  v = wave_reduce_sum(v);
  int tid = threadIdx.x;
  if ((tid & 63) == 0) red[tid >> 6] = v;
  __syncthreads();
  v = red[0] + red[1] + red[2] + red[3];
  __syncthreads();
  return v;
}

DEV float gelu_exact(float x) {
  return 0.5f * x * (1.f + erff(x * 0.70710678118654752f));
}

// ---------------------------------------------------------------------------
// prep_kernel: all one-shot setup, block-range dispatched. 256 threads.
//  blk 0..431   : qkv weight+bias fold (216/layer: by 0..7 = W rows,
//                 by==8 = b_exp pseudo-row) 32x64 tiles, K=512, reg-dbuf
//  blk 432..943 : edge LN (b,i): 256 threads, vals[32]/thread
//  blk 944..1007: wfold W2 tile (l,h,nt), d-tiled 2x32
//  blk 1008..1015: wfold b_out2 (l,nt)
//  blk 1016..1031: rope tables
//  blk 1032..1543: LN0 row (xln + nodes copy)
__global__ __launch_bounds__(256) void prep_kernel(
    const float* __restrict__ edges, const float* __restrict__ eg,
    const float* __restrict__ eb, float* __restrict__ e,
    float* __restrict__ eT, float* __restrict__ cost, float* __restrict__ sint,
    const float* __restrict__ nodes_in, const float* __restrict__ ln1_g,
    const float* __restrict__ ln1_b, float* __restrict__ xln,
    float* __restrict__ nodes, const float* __restrict__ wek,
    const float* __restrict__ w_out, const float* __restrict__ bek,
    const float* __restrict__ b_out, float* __restrict__ W2,
    float* __restrict__ b_out2, const float* __restrict__ w_exp,
    const float* __restrict__ b_exp, const float* __restrict__ w_q,
    const float* __restrict__ b_q, const float* __restrict__ w_kv,
    const float* __restrict__ b_kv, float* __restrict__ WqkvF,
    float* __restrict__ bqkvF) {
  __shared__ __align__(16) float smem[4736];  // 18.9 KB, aliased per role
  int blk = blockIdx.x;
  int tid = threadIdx.x;

  if (blk < 432) {  // ---- qkv weight+bias fold: 32x64 tile, K=512, dbuf ----
    int t = blk;  // 0..431
    int l = t / 216, r = t % 216;
    int by = r / 24, bx = r % 24;
    bool biasrow = (by == 8);
    float* As = smem;            // [32][34]
    float* Bs = smem + 32 * 34;  // [32][68]
    int n0 = bx * 64;
    const float* Aab = w_exp + (size_t)l * 256 * 512 + (size_t)(by * 32) * 512;
    const float* be = b_exp + l * 512;
    const float* Wb;
    int ldw;
    if (n0 < 512) {
      Wb = w_q + (size_t)l * 512 * 512 + n0;
      ldw = 512;
    } else {
      Wb = w_kv + (size_t)l * 512 * 1024 + (n0 - 512);
      ldw = 1024;
    }
    int arow = tid >> 3, acol = (tid & 7) << 2;
    int brow = tid >> 4, bcol = (tid & 15) << 2;
    int tx = tid & 15, ty = tid >> 4;
    auto lda = [&](int kpos) -> float4 {
      return biasrow ? *(const float4*)(be + kpos + acol)
                     : *(const float4*)(Aab + (size_t)arow * 512 + kpos + acol);
    };
    float4 a_nxt = lda(0);
    float4 b0_nxt = *(const float4*)(Wb + (size_t)brow * ldw + bcol);
    float4 b1_nxt = *(const float4*)(Wb + (size_t)(brow + 16) * ldw + bcol);
    float acc[2][4] = {};
    for (int k0 = 0; k0 < 512; k0 += 32) {
      As[(acol + 0) * 34 + arow] = a_nxt.x;
      As[(acol + 1) * 34 + arow] = a_nxt.y;
      As[(acol + 2) * 34 + arow] = a_nxt.z;
      As[(acol + 3) * 34 + arow] = a_nxt.w;
      *(float4*)&Bs[brow * 68 + bcol] = b0_nxt;
      *(float4*)&Bs[(brow + 16) * 68 + bcol] = b1_nxt;
      __syncthreads();
      int kn = k0 + 32;
      if (kn < 512) {
        a_nxt = lda(kn);
        b0_nxt = *(const float4*)(Wb + (size_t)(kn + brow) * ldw + bcol);
        b1_nxt = *(const float4*)(Wb + (size_t)(kn + brow + 16) * ldw + bcol);
      }
#pragma unroll
      for (int kk = 0; kk < 32; ++kk) {
        float2 av = *(const float2*)&As[kk * 34 + ty * 2];
        float4 bv = *(const float4*)&Bs[kk * 68 + tx * 4];
        acc[0][0] += av.x * bv.x;
        acc[0][1] += av.x * bv.y;
        acc[0][2] += av.x * bv.z;
        acc[0][3] += av.x * bv.w;
        acc[1][0] += av.y * bv.x;
        acc[1][1] += av.y * bv.y;
        acc[1][2] += av.y * bv.z;
        acc[1][3] += av.y * bv.w;
      }
      __syncthreads();
    }
    if (!biasrow) {
#pragma unroll
      for (int u = 0; u < 2; ++u) {
        int d = by * 32 + ty * 2 + u;
        float4 o = {acc[u][0], acc[u][1], acc[u][2], acc[u][3]};
        *(float4*)(WqkvF + (size_t)l * 256 * 1536 + (size_t)d * 1536 + n0 +
                   tx * 4) = o;
      }
    } else if (ty == 0) {
      // pseudo-row d==0 (u==0) holds the b_exp dot; add base q/kv bias.
#pragma unroll
      for (int w = 0; w < 4; ++w) {
        int n = n0 + tx * 4 + w;
        float bb = (n < 512) ? b_q[l * 512 + n] : b_kv[l * 1024 + (n - 512)];
        bqkvF[l * 1536 + n] = acc[0][w] + bb;
      }
    }
  } else if (blk < 944) {  // ---- edge LN: 256 threads, no spill ----
    float* ets = smem;          // [128][33] = 4224
    float* redS = smem + 4224;  // 256
    float* redQ = smem + 4480;  // 256
    int eidx = blk - 432;
    int i = eidx & 127, b = eidx >> 7;
    int j = tid & 127, half = tid >> 7;
    const float* src = edges + (size_t)b * EDGEn * Nn * Nn +
                       (size_t)(half * 32) * (Nn * Nn) + i * Nn + j;
    float vals[32];
    float s = 0.f, q = 0.f;
#pragma unroll
    for (int cc = 0; cc < 32; ++cc) {
      float x = src[(size_t)cc * (Nn * Nn)];
      vals[cc] = x;
      s += x;
      q += x * x;
    }
    redS[tid] = s;
    redQ[tid] = q;
    __syncthreads();
    float ts = redS[j] + redS[j + 128];
    float tq = redQ[j] + redQ[j + 128];
    float m = ts * (1.0f / 64.0f);
    float var = tq * (1.0f / 64.0f) - m * m;
    float inv = 1.f / sqrtf(var + 1e-5f);
    float* dst = e + ((size_t)(b * Nn + i) * EDGEn) * Nn + j;
#pragma unroll
    for (int cc = 0; cc < 32; ++cc) {
      int c = half * 32 + cc;
      float o = (vals[cc] - m) * inv * eg[c] + eb[c];
      vals[cc] = o;
      dst[(size_t)c * Nn] = o;
    }
    float* dstT = eT + ((size_t)(b * Nn + i) * Nn) * EDGEn;
#pragma unroll
    for (int ch = 0; ch < 2; ++ch) {
      __syncthreads();  // guard ets reuse (and redS/redQ reads on pass 0)
      if (half == ch) {
#pragma unroll
        for (int cc = 0; cc < 32; ++cc) ets[j * 33 + cc] = vals[cc];
      }
      __syncthreads();
#pragma unroll
      for (int it = 0; it < 4; ++it) {
        int f4 = it * 256 + tid;  // 1024 float4s: 128 j x 8 c4
        int jj = f4 >> 3, c4 = (f4 & 7) << 2;
        float4 o4 = {ets[jj * 33 + c4], ets[jj * 33 + c4 + 1],
                     ets[jj * 33 + c4 + 2], ets[jj * 33 + c4 + 3]};
        *(float4*)(dstT + (size_t)jj * EDGEn + ch * 32 + c4) = o4;
      }
    }
  } else if (blk < 1008) {  // ---- wfold W2, d-tiled 2x32 ----
    int t = blk - 944;
    int l = t >> 5, h = (t >> 2) & 7, nt = t & 3;
    float* As = smem;            // [64][36] = 2304
    float* Bs = smem + 2304;     // [32][68] = 2176
    const float* wekl = wek + (size_t)l * 64 * 512 + h * 64;
    const float* woutl =
        w_out + (size_t)l * 512 * 256 + (size_t)(h * 64) * 256 + nt * 64;
    int tx = tid & 15, ty = tid >> 4;
    float acc[4][4] = {};
    for (int d0 = 0; d0 < 64; d0 += 32) {
      for (int f = tid; f < 512; f += 256) {
        int c = f >> 3, d4 = (f & 7) << 2;
        *(float4*)&As[c * 36 + d4] =
            *(const float4*)(wekl + (size_t)c * 512 + d0 + d4);
      }
      for (int f = tid; f < 512; f += 256) {
        int dd = f >> 4, n4 = (f & 15) << 2;
        *(float4*)&Bs[dd * 68 + n4] =
            *(const float4*)(woutl + (size_t)(d0 + dd) * 256 + n4);
      }
      __syncthreads();
#pragma unroll
      for (int dd = 0; dd < 32; ++dd) {
        float4 bv = *(const float4*)&Bs[dd * 68 + tx * 4];
#pragma unroll
        for (int u = 0; u < 4; ++u) {
          float a = As[(ty * 4 + u) * 36 + dd];
          acc[u][0] += a * bv.x;
          acc[u][1] += a * bv.y;
          acc[u][2] += a * bv.z;
          acc[u][3] += a * bv.w;
        }
      }
      __syncthreads();
    }
#pragma unroll
    for (int u = 0; u < 4; ++u) {
      float4 o = {acc[u][0], acc[u][1], acc[u][2], acc[u][3]};
      *(float4*)(W2 + (size_t)l * 512 * 256 +
                 (size_t)(h * 64 + ty * 4 + u) * 256 + nt * 64 + tx * 4) = o;
    }
  } else if (blk < 1016) {  // ---- wfold b_out2 ----
    int t = blk - 1008;
    int l = t >> 2, nt = t & 3;
    float* part = smem;
    int nn = tid & 63, kq = tid >> 6;
    const float* wcol = w_out + (size_t)l * 512 * 256 + nt * 64 + nn;
    float acc = 0.f;
    for (int k = kq * 128; k < kq * 128 + 128; ++k)
      acc += bek[l * 512 + k] * wcol[(size_t)k * 256];
    part[tid] = acc;
    __syncthreads();
    if (tid < 64)
      b_out2[l * 256 + nt * 64 + nn] =
          b_out[l * 256 + nt * 64 + nn] + part[nn] + part[64 + nn] +
          part[128 + nn] + part[192 + nn];
  } else if (blk < 1032) {  // ---- rope tables ----
    int t = (blk - 1016) * 256 + tid;
    if (t < Nn * 32) {
      int n = t >> 5, p = t & 31;
      float inv = powf(10000.f, -(float)(2 * p) / 64.f);
      float fr = (float)n * inv;
      cost[t] = cosf(fr);
      sint[t] = sinf(fr);
    }
  } else {  // ---- LN0 + nodes copy ----
    float* red = smem;
    int row = blk - 1032;
    float v = nodes_in[(size_t)row * DIMn + tid];
    nodes[(size_t)row * DIMn + tid] = v;
    float m = block_reduce_sum_256(v, red) * (1.0f / 256.0f);
    float d = v - m;
    float var = block_reduce_sum_256(d * d, red) * (1.0f / 256.0f);
    float inv = 1.f / sqrtf(var + 1e-5f);
    xln[(size_t)row * DIMn + tid] = d * inv * ln1_g[tid] + ln1_b[tid];
  }
}

// ---------------------------------------------------------------------------
// fp32 GEMM, 32x64 tile, BK=32, 2x4 microtile, register double-buffered.
// A2: A-stage sums two partials; aact==1: gelu after the sum.
// Dual-N (W2n at col>=N1), dual-K (k>=Ksplit reads Wkb), split-K via z.
// act: 0 none, 1 exact gelu, 4 qkv mode (rope cols<1024; k section -> kT).
__global__ __launch_bounds__(256) void gemm_kernel(
    const float* __restrict__ A, const float* __restrict__ A2, int aact,
    const float* __restrict__ W1, int N1, const float* __restrict__ b1,
    const float* __restrict__ W2n, int N2, const float* __restrict__ b2,
    const float* __restrict__ Wkb, int Ksplit, float* __restrict__ C, int M,
    int Ntot, int K, int kspan, int act, const float* __restrict__ cost,
    const float* __restrict__ sint, float* __restrict__ kT) {
  __shared__ float As[32][34];
  __shared__ __align__(16) float Bs[32][68];
  int tid = threadIdx.x;
  int bx = blockIdx.x, by = blockIdx.y, zid = blockIdx.z;
  int tx = tid & 15, ty = tid >> 4;
  int arow = tid >> 3, acol = (tid & 7) << 2;
  int brow = tid >> 4, bcol = (tid & 15) << 2;
  int col0 = bx * 64;
  const float* W = W1;
  const float* bias = b1;
  int Nw = N1, wcol = col0;
  if (W2n && col0 >= N1) {
    W = W2n;
    bias = b2;
    Nw = N2;
    wcol = col0 - N1;
  }
  int kb = zid * kspan, kend = kb + kspan;
  const float* arp = A + (size_t)(by * 32 + arow) * K;
  const float* arp2 = A2 ? A2 + (size_t)(by * 32 + arow) * K : nullptr;

  auto load_a = [&](int kpos) -> float4 {
    float4 a = *(const float4*)(arp + kpos + acol);
    if (arp2) {
      float4 a2 = *(const float4*)(arp2 + kpos + acol);
      a.x += a2.x;
      a.y += a2.y;
      a.z += a2.z;
      a.w += a2.w;
    }
    if (aact == 1) {
      a.x = gelu_exact(a.x);
      a.y = gelu_exact(a.y);
      a.z = gelu_exact(a.z);
      a.w = gelu_exact(a.w);
    }
    return a;
  };

  float4 a_nxt = load_a(kb);
  const float* w0p;
  const float* w1p;
  {
    int kr0 = kb + brow, kr1 = kb + brow + 16;
    w0p = (Ksplit && kr0 >= Ksplit)
              ? Wkb + (size_t)(kr0 - Ksplit) * Nw + wcol + bcol
              : W + (size_t)kr0 * Nw + wcol + bcol;
    w1p = (Ksplit && kr1 >= Ksplit)
              ? Wkb + (size_t)(kr1 - Ksplit) * Nw + wcol + bcol
              : W + (size_t)kr1 * Nw + wcol + bcol;
  }
  float4 b0_nxt = *(const float4*)w0p;
  float4 b1_nxt = *(const float4*)w1p;

  float acc[2][4] = {};
  for (int k0 = kb; k0 < kend; k0 += 32) {
    As[acol + 0][arow] = a_nxt.x;
    As[acol + 1][arow] = a_nxt.y;
    As[acol + 2][arow] = a_nxt.z;
    As[acol + 3][arow] = a_nxt.w;
    *(float4*)&Bs[brow][bcol] = b0_nxt;
    *(float4*)&Bs[brow + 16][bcol] = b1_nxt;
    __syncthreads();
    int kn = k0 + 32;
    if (kn < kend) {
      a_nxt = load_a(kn);
      int kr0 = kn + brow, kr1 = kn + brow + 16;
      w0p = (Ksplit && kr0 >= Ksplit)
                ? Wkb + (size_t)(kr0 - Ksplit) * Nw + wcol + bcol
                : W + (size_t)kr0 * Nw + wcol + bcol;
      w1p = (Ksplit && kr1 >= Ksplit)
                ? Wkb + (size_t)(kr1 - Ksplit) * Nw + wcol + bcol
                : W + (size_t)kr1 * Nw + wcol + bcol;
      b0_nxt = *(const float4*)w0p;
      b1_nxt = *(const float4*)w1p;
    }
#pragma unroll
    for (int kk = 0; kk < 32; ++kk) {
      float2 av = *(const float2*)&As[kk][ty * 2];
      float4 bv = *(const float4*)&Bs[kk][tx * 4];
      acc[0][0] += av.x * bv.x;
      acc[0][1] += av.x * bv.y;
      acc[0][2] += av.x * bv.z;
      acc[0][3] += av.x * bv.w;
      acc[1][0] += av.y * bv.x;
      acc[1][1] += av.y * bv.y;
      acc[1][2] += av.y * bv.z;
      acc[1][3] += av.y * bv.w;
    }
    __syncthreads();
  }
  int ccol = wcol + tx * 4;
  bool ksec = (act == 4) && (col0 >= 512) && (col0 < 1024);
  float* trans = (float*)Bs;
  float* Cz = C + (size_t)zid * M * Ntot;
#pragma unroll
  for (int u = 0; u < 2; ++u) {
    int r = by * 32 + ty * 2 + u;
    float o[4];
#pragma unroll
    for (int w = 0; w < 4; ++w)
      o[w] = acc[u][w] + (zid == 0 ? bias[ccol + w] : 0.f);
    if (act == 1) {
#pragma unroll
      for (int w = 0; w < 4; ++w) o[w] = gelu_exact(o[w]);
    } else if (act == 4 && col0 < 1024) {
      int n = r & 127;
      int p0 = (ccol & 63) >> 1;
      float c0 = cost[n * 32 + p0], s0 = sint[n * 32 + p0];
      float c1 = cost[n * 32 + p0 + 1], s1 = sint[n * 32 + p0 + 1];
      float x0 = o[0], x1 = o[1], x2 = o[2], x3 = o[3];
      o[0] = x0 * c0 - x1 * s0;
      o[1] = x1 * c0 + x0 * s0;
      o[2] = x2 * c1 - x3 * s1;
      o[3] = x3 * c1 + x2 * s1;
    }
    if (ksec) {
#pragma unroll
      for (int w = 0; w < 4; ++w) trans[(tx * 4 + w) * 33 + ty * 2 + u] = o[w];
    } else {
      float4 o4 = {o[0], o[1], o[2], o[3]};
      *(float4*)(Cz + (size_t)r * Ntot + col0 + tx * 4) = o4;
    }
  }
  if (ksec) {
    __syncthreads();
    int h = (col0 - 512) >> 6;
    int bb = (by * 32) >> 7;
#pragma unroll
    for (int q = 0; q < 2; ++q) {
      int f4 = tid * 2 + q;
      int dl = f4 >> 3, j4 = (f4 & 7) << 2;
      int jj = (by * 32 + j4) & 127;
      float4 o4 = {trans[dl * 33 + j4], trans[dl * 33 + j4 + 1],
                   trans[dl * 33 + j4 + 2], trans[dl * 33 + j4 + 3]};
      *(float4*)(kT + ((size_t)(bb * 8 + h) * 64 + dl) * 128 + jj) = o4;
    }
  }
}

// ---------------------------------------------------------------------------
// Attention + qe + out-proj partial. Block per (b, head-PAIR, i-quad), 128
// threads. Per-head math identical to R13; e/eT elements loaded once per
// thread and used for BOTH heads (halves the dominant L2 traffic term).
// Writes per-head proj partial: proj[h*PART + row*256 + n].
__global__ __launch_bounds__(128) void attn_kernel(
    const float* __restrict__ qkv, const float* __restrict__ e,
    const float* __restrict__ eT, const float* __restrict__ kT,
    const float* __restrict__ wek, const float* __restrict__ w_out,
    const float* __restrict__ W2, float* __restrict__ proj) {
  __shared__ __align__(16) float qs[2][256];
  __shared__ __align__(16) float qes[2][256];
  __shared__ __align__(16) float att[2][512];
  __shared__ float avh[2][512];
  __shared__ float aeh[2][512];
  __shared__ float wekh[64 * 65];
  int blk = blockIdx.x;
  int iq = blk & 31;
  int bh2 = blk >> 5;
  int hp = bh2 & 3, b = bh2 >> 2;
  int h0 = hp * 2;
  int i0 = iq * 4;
  int row0 = b * 128 + i0;
  int tid = threadIdx.x;

  for (int f = tid; f < 512; f += 128) {
    int hh = f >> 8, ii = (f >> 6) & 3, d = f & 63;
    qs[hh][ii * 64 + d] =
        qkv[(size_t)(row0 + ii) * QKVW + (h0 + hh) * 64 + d];
  }
  __syncthreads();

  // qe per head (wekh staged sequentially to halve LDS)
#pragma unroll
  for (int hh = 0; hh < 2; ++hh) {
    for (int f = tid; f < 4096; f += 128) {
      int c = f >> 6, d = f & 63;
      wekh[c * 65 + d] = wek[(size_t)c * INNERn + (h0 + hh) * 64 + d];
    }
    __syncthreads();
    for (int f = tid; f < 256; f += 128) {
      int ii = f >> 6, c = f & 63;
      float acc = 0.f;
#pragma unroll
      for (int d = 0; d < 64; ++d)
        acc += qs[hh][ii * 64 + d] * wekh[c * 65 + d];
      qes[hh][f] = acc;
    }
    __syncthreads();
  }

  int i2 = tid >> 5, j4 = tid & 31;
  {
    float s[2][4] = {};
    const float* ktb0 = kT + (size_t)(b * 8 + h0) * 8192 + j4 * 4;
#pragma unroll
    for (int d4 = 0; d4 < 64; d4 += 4) {
      float4 qa = *(const float4*)&qs[0][i2 * 64 + d4];
      float4 qb = *(const float4*)&qs[1][i2 * 64 + d4];
#pragma unroll
      for (int t = 0; t < 4; ++t) {
        float4 k0 = *(const float4*)(ktb0 + (size_t)(d4 + t) * 128);
        float4 k1 = *(const float4*)(ktb0 + 8192 + (size_t)(d4 + t) * 128);
        float qa_t = ((const float*)&qa)[t];
        float qb_t = ((const float*)&qb)[t];
        s[0][0] += qa_t * k0.x;
        s[0][1] += qa_t * k0.y;
        s[0][2] += qa_t * k0.z;
        s[0][3] += qa_t * k0.w;
        s[1][0] += qb_t * k1.x;
        s[1][1] += qb_t * k1.y;
        s[1][2] += qb_t * k1.z;
        s[1][3] += qb_t * k1.w;
      }
    }
    const float* ebp = e + (size_t)(row0 + i2) * 8192 + j4 * 4;
#pragma unroll
    for (int c4 = 0; c4 < 64; c4 += 4) {
      float4 qea = *(const float4*)&qes[0][i2 * 64 + c4];
      float4 qeb = *(const float4*)&qes[1][i2 * 64 + c4];
#pragma unroll
      for (int t = 0; t < 4; ++t) {
        float4 ev = *(const float4*)(ebp + (size_t)(c4 + t) * 128);  // shared
        float qa_t = ((const float*)&qea)[t];
        float qb_t = ((const float*)&qeb)[t];
        s[0][0] += qa_t * ev.x;
        s[0][1] += qa_t * ev.y;
        s[0][2] += qa_t * ev.z;
        s[0][3] += qa_t * ev.w;
        s[1][0] += qb_t * ev.x;
        s[1][1] += qb_t * ev.y;
        s[1][2] += qb_t * ev.z;
        s[1][3] += qb_t * ev.w;
      }
    }
#pragma unroll
    for (int hh = 0; hh < 2; ++hh) {
      float s0 = s[hh][0] * 0.125f, s1 = s[hh][1] * 0.125f,
            s2 = s[hh][2] * 0.125f, s3 = s[hh][3] * 0.125f;
      float mx = fmaxf(fmaxf(s0, s1), fmaxf(s2, s3));
#pragma unroll
      for (int m = 16; m >= 1; m >>= 1) mx = fmaxf(mx, __shfl_xor(mx, m));
      float p0 = expf(s0 - mx), p1 = expf(s1 - mx), p2 = expf(s2 - mx),
            p3 = expf(s3 - mx);
      float sm = p0 + p1 + p2 + p3;
#pragma unroll
      for (int m = 16; m >= 1; m >>= 1) sm += __shfl_xor(sm, m);
      float inv = 1.f / sm;
      float4 a4 = {p0 * inv, p1 * inv, p2 * inv, p3 * inv};
      *(float4*)&att[hh][i2 * 128 + j4 * 4] = a4;
    }
  }
  __syncthreads();

  {
    int d = tid & 63, half = tid >> 6;
    float av[2][4] = {}, ae[2][4] = {};
    const float* vb0 =
        qkv + (size_t)(b * 128) * QKVW + 1024 + h0 * 64 + d;
    const float* etb = eT + ((size_t)row0 * 128) * 64 + d;
    for (int jq = 0; jq < 16; ++jq) {
      int jb = half * 64 + jq * 4;
      float4 a00 = *(const float4*)&att[0][0 * 128 + jb];
      float4 a01 = *(const float4*)&att[0][1 * 128 + jb];
      float4 a02 = *(const float4*)&att[0][2 * 128 + jb];
      float4 a03 = *(const float4*)&att[0][3 * 128 + jb];
      float4 a10 = *(const float4*)&att[1][0 * 128 + jb];
      float4 a11 = *(const float4*)&att[1][1 * 128 + jb];
      float4 a12 = *(const float4*)&att[1][2 * 128 + jb];
      float4 a13 = *(const float4*)&att[1][3 * 128 + jb];
#pragma unroll
      for (int t = 0; t < 4; ++t) {
        int j = jb + t;
        float v0 = vb0[(size_t)j * QKVW];
        float v1 = vb0[(size_t)j * QKVW + 64];
        float e0 = etb[(size_t)j * 64];            // shared between heads
        float e1 = etb[8192 + (size_t)j * 64];
        float e2 = etb[16384 + (size_t)j * 64];
        float e3 = etb[24576 + (size_t)j * 64];
        float a0t0 = ((const float*)&a00)[t];
        float a0t1 = ((const float*)&a01)[t];
        float a0t2 = ((const float*)&a02)[t];
        float a0t3 = ((const float*)&a03)[t];
        float a1t0 = ((const float*)&a10)[t];
        float a1t1 = ((const float*)&a11)[t];
        float a1t2 = ((const float*)&a12)[t];
        float a1t3 = ((const float*)&a13)[t];
        av[0][0] += a0t0 * v0;
        av[0][1] += a0t1 * v0;
        av[0][2] += a0t2 * v0;
        av[0][3] += a0t3 * v0;
        av[1][0] += a1t0 * v1;
        av[1][1] += a1t1 * v1;
        av[1][2] += a1t2 * v1;
        av[1][3] += a1t3 * v1;
        ae[0][0] += a0t0 * e0;
        ae[0][1] += a0t1 * e1;
        ae[0][2] += a0t2 * e2;
        ae[0][3] += a0t3 * e3;
        ae[1][0] += a1t0 * e0;
        ae[1][1] += a1t1 * e1;
        ae[1][2] += a1t2 * e2;
        ae[1][3] += a1t3 * e3;
      }
    }
#pragma unroll
    for (int hh = 0; hh < 2; ++hh) {
#pragma unroll
      for (int r = 0; r < 4; ++r) {
        avh[hh][half * 256 + r * 64 + d] = av[hh][r];
        aeh[hh][half * 256 + r * 64 + d] = ae[hh][r];
      }
    }
  }
  __syncthreads();

  for (int f = tid; f < 512; f += 128) {
    int hh = f >> 8, ii = (f >> 6) & 3, dd = f & 63;
    att[hh][ii * 128 + dd] =
        avh[hh][ii * 64 + dd] + avh[hh][256 + ii * 64 + dd];
    att[hh][ii * 128 + 64 + dd] =
        aeh[hh][ii * 64 + dd] + aeh[hh][256 + ii * 64 + dd];
  }
  __syncthreads();

#pragma unroll
  for (int hh = 0; hh < 2; ++hh) {
    int rp = tid >> 6, n4 = (tid & 63) << 2;
    int r0 = rp * 2, r1 = rp * 2 + 1;
    float o0[4] = {}, o1[4] = {};
    const float* wo = w_out + (size_t)((h0 + hh) * 64) * 256 + n4;
#pragma unroll 8
    for (int k = 0; k < 64; ++k) {
      float4 w4 = *(const float4*)(wo + (size_t)k * 256);
      float a0 = att[hh][r0 * 128 + k];
      float a1 = att[hh][r1 * 128 + k];
      o0[0] += a0 * w4.x;
      o0[1] += a0 * w4.y;
      o0[2] += a0 * w4.z;
      o0[3] += a0 * w4.w;
      o1[0] += a1 * w4.x;
      o1[1] += a1 * w4.y;
      o1[2] += a1 * w4.z;
      o1[3] += a1 * w4.w;
    }
    const float* w2 = W2 + (size_t)((h0 + hh) * 64) * 256 + n4;
#pragma unroll 8
    for (int k = 0; k < 64; ++k) {
      float4 w4 = *(const float4*)(w2 + (size_t)k * 256);
      float a0 = att[hh][r0 * 128 + 64 + k];
      float a1 = att[hh][r1 * 128 + 64 + k];
      o0[0] += a0 * w4.x;
      o0[1] += a0 * w4.y;
      o0[2] += a0 * w4.z;
      o0[3] += a0 * w4.w;
      o1[0] += a1 * w4.x;
      o1[1] += a1 * w4.y;
      o1[2] += a1 * w4.z;
      o1[3] += a1 * w4.w;
    }
    float* pp = proj + (size_t)(h0 + hh) * PART;
    float4 v0 = {o0[0], o0[1], o0[2], o0[3]};
    float4 v1 = {o1[0], o1[1], o1[2], o1[3]};
    *(float4*)(pp + (size_t)(row0 + r0) * 256 + n4) = v0;
    *(float4*)(pp + (size_t)(row0 + r1) * 256 + n4) = v1;
  }
}

// ---------------------------------------------------------------------------
// Gated residual + optional fused LN. x = sum of nparts partials (+ badd).
__global__ __launch_bounds__(256) void gate_ln_kernel(
    const float* __restrict__ x, int nparts, const float* __restrict__ badd,
    float* __restrict__ nodes, const float* __restrict__ gw,
    const float* __restrict__ lng, const float* __restrict__ lnb,
    float* __restrict__ xln) {
  __shared__ float red[4];
  int row = blockIdx.x, tid = threadIdx.x;
  size_t off = (size_t)row * DIMn + tid;
  float xv = x[off];
  for (int p = 1; p < nparts; ++p) xv += x[off + (size_t)p * PART];
  if (badd) xv += badd[tid];
  float rv = nodes[off];
  float pv =
      xv * gw[tid] + rv * gw[DIMn + tid] + (xv - rv) * gw[2 * DIMn + tid];
  float ssum = block_reduce_sum_256(pv, red);
  float gsig = 1.f / (1.f + expf(-ssum));
  float nv = xv * gsig + rv * (1.f - gsig);
  nodes[off] = nv;
  if (lng) {
    float m = block_reduce_sum_256(nv, red) * (1.0f / 256.0f);
    float d = nv - m;
    float var = block_reduce_sum_256(d * d, red) * (1.0f / 256.0f);
    float inv = 1.f / sqrtf(var + 1e-5f);
    xln[off] = d * inv * lng[tid] + lnb[tid];
  }
}

// ---------------------------------------------------------------------------
// VQ nearest neighbor: thread-per-codebook-entry, 4 rows per block.
__global__ __launch_bounds__(256) void vq_kernel(
    const float* __restrict__ nodes, const float* __restrict__ codebook,
    float* __restrict__ out) {
  __shared__ __align__(16) float zs[4 * 256];
  __shared__ float wval[4][4];
  __shared__ int widx[4][4];
  __shared__ int fidx[4];
  int row0 = blockIdx.x * 4;
  int tid = threadIdx.x;
  for (int f = tid; f < 1024; f += 256) zs[f] = nodes[(size_t)row0 * DIMn + f];
  __syncthreads();
  int k1 = tid, k2 = tid + 256;
  const float4* c1p = (const float4*)(codebook + (size_t)k1 * DIMn);
  const float4* c2p = (const float4*)(codebook + (size_t)k2 * DIMn);
  float dot[4][2] = {};
  float cc0 = 0.f, cc1 = 0.f;
#pragma unroll 8
  for (int d4 = 0; d4 < 64; ++d4) {
    float4 c1 = c1p[d4], c2 = c2p[d4];
    cc0 += c1.x * c1.x + c1.y * c1.y + c1.z * c1.z + c1.w * c1.w;
    cc1 += c2.x * c2.x + c2.y * c2.y + c2.z * c2.z + c2.w * c2.w;
#pragma unroll
    for (int r = 0; r < 4; ++r) {
      float4 z = *(const float4*)&zs[r * 256 + d4 * 4];
      dot[r][0] += c1.x * z.x + c1.y * z.y + c1.z * z.z + c1.w * z.w;
      dot[r][1] += c2.x * z.x + c2.y * z.y + c2.z * z.z + c2.w * z.w;
    }
  }
  int lane = tid & 63, w = tid >> 6;
#pragma unroll
  for (int r = 0; r < 4; ++r) {
    float bv = cc0 - 2.f * dot[r][0];
    int bi = k1;
    float v2 = cc1 - 2.f * dot[r][1];
    if (v2 < bv) {
      bv = v2;
      bi = k2;
    }
#pragma unroll
    for (int m = 32; m >= 1; m >>= 1) {
      float ov = __shfl_xor(bv, m);
      int oi = __shfl_xor(bi, m);
      if (ov < bv || (ov == bv && oi < bi)) {
        bv = ov;
        bi = oi;
      }
    }
    if (lane == 0) {
      wval[r][w] = bv;
      widx[r][w] = bi;
    }
  }
  __syncthreads();
  if (tid < 4) {
    float bb = wval[tid][0];
    int bi = widx[tid][0];
    for (int t = 1; t < 4; ++t)
      if (wval[tid][t] < bb || (wval[tid][t] == bb && widx[tid][t] < bi)) {
        bb = wval[tid][t];
        bi = widx[tid][t];
      }
    fidx[tid] = bi;
  }
  __syncthreads();
  for (int f = tid; f < 1024; f += 256) {
    int r = f >> 8, d = f & 255;
    float zv = zs[f];
    float zq = codebook[(size_t)fidx[r] * DIMn + d];
    out[(size_t)(row0 + r) * DIMn + d] = zv + (zq - zv);
  }
}

// ---------------------------------------------------------------------------
extern "C" void kernel_launch(void* const* d_in, const int* in_sizes, int n_in,
                              void* d_out, int out_size, void* d_ws,
                              size_t ws_size, hipStream_t stream) {
  const float* nodes_in = (const float*)d_in[0];
  const float* edges = (const float*)d_in[1];
  const float* edge_ln_g = (const float*)d_in[2];
  const float* edge_ln_b = (const float*)d_in[3];
  const float* ln1_g = (const float*)d_in[4];
  const float* ln1_b = (const float*)d_in[5];
  const float* w_exp = (const float*)d_in[6];
  const float* b_exp = (const float*)d_in[7];
  const float* w_q = (const float*)d_in[8];
  const float* b_q = (const float*)d_in[9];
  const float* w_kv = (const float*)d_in[10];
  const float* b_kv = (const float*)d_in[11];
  const float* w_ekv = (const float*)d_in[12];
  const float* b_ekv = (const float*)d_in[13];
  const float* w_out = (const float*)d_in[14];
  const float* b_out = (const float*)d_in[15];
  const float* gate1_w = (const float*)d_in[16];
  const float* ln2_g = (const float*)d_in[17];
  const float* ln2_b = (const float*)d_in[18];
  const float* w_ff1 = (const float*)d_in[19];
  const float* b_ff1 = (const float*)d_in[20];
  const float* w_ff2 = (const float*)d_in[21];
  const float* b_ff2 = (const float*)d_in[22];
  const float* gate2_w = (const float*)d_in[23];
  const float* codebook = (const float*)d_in[24];

  float* ws = (float*)d_ws;
  float* e_buf = ws;                  // 4194304
  float* eT_buf = e_buf + 4194304;    // 4194304
  float* cost = eT_buf + 4194304;     // 4096
  float* sint = cost + 4096;          // 4096
  float* nodes = sint + 4096;         // 131072
  float* xln = nodes + 131072;        // 131072
  float* qkvb = xln + 131072;         // 786432
  float* kTb = qkvb + 786432;         // 262144
  float* proj = kTb + 262144;         // 1048576 (8 per-head / 4 splitK parts)
  float* ff1 = proj + 1048576;        // 1048576 (2 split-K partials)
  float* W2buf = ff1 + 1048576;       // 262144
  float* bout2 = W2buf + 262144;      // 512
  float* WqkvF = bout2 + 512;         // 786432 (2 layers x 256 x 1536)
  float* bqkvF = WqkvF + 786432;      // 3072

  // one-shot setup: fold (weight+bias) first, edge LN, W2, rope, LN0 fillers
  prep_kernel<<<1544, 256, 0, stream>>>(
      edges, edge_ln_g, edge_ln_b, e_buf, eT_buf, cost, sint, nodes_in, ln1_g,
      ln1_b, xln, nodes, w_ekv, w_out, b_ekv, b_out, W2buf, bout2, w_exp,
      b_exp, w_q, b_q, w_kv, b_kv, WqkvF, bqkvF);

  for (int l = 0; l < DEPTHn; ++l) {
    // fused q|kv directly from xln via folded weights (K=256), rope + kT
    gemm_kernel<<<dim3(24, 16, 1), 256, 0, stream>>>(
        xln, nullptr, 0, WqkvF + (size_t)l * 256 * 1536, 1536,
        bqkvF + l * 1536, nullptr, 0, nullptr, nullptr, 0, qkvb, 512, QKVW,
        256, 256, 4, cost, sint, kTb);
    // attention: head-pair blocks (+qe, +out-proj per-head partials)
    attn_kernel<<<512, 128, 0, stream>>>(qkvb, e_buf, eT_buf, kTb,
                                         w_ekv + l * 64 * 512,
                                         w_out + l * 512 * 256,
                                         W2buf + l * 512 * 256, proj);
    gate_ln_kernel<<<512, 256, 0, stream>>>(
        proj, 8, bout2 + l * 256, nodes, gate1_w + l * 768, ln2_g + l * 256,
        ln2_b + l * 256, xln);
    // ff1: split-K x2 (gelu deferred to ff2 A-stage)
    gemm_kernel<<<dim3(16, 16, 2), 256, 0, stream>>>(
        xln, nullptr, 0, w_ff1 + l * 256 * 1024, 1024, b_ff1 + l * 1024,
        nullptr, 0, nullptr, nullptr, 0, ff1, 512, 1024, 256, 128, 0, cost,
        sint, nullptr);
    // ff2: A = gelu(ff1 p0 + p1), split-K x4 -> proj partials
    gemm_kernel<<<dim3(4, 16, 4), 256, 0, stream>>>(
        ff1, ff1 + 524288, 1, w_ff2 + l * 1024 * 256, 256, b_ff2 + l * 256,
        nullptr, 0, nullptr, nullptr, 0, proj, 512, 256, 1024, 256, 0, cost,
        sint, nullptr);
    const float* nlng = (l + 1 < DEPTHn) ? ln1_g + (l + 1) * 256 : nullptr;
    const float* nlnb = (l + 1 < DEPTHn) ? ln1_b + (l + 1) * 256 : nullptr;
    gate_ln_kernel<<<512, 256, 0, stream>>>(proj, 4, nullptr, nodes,
                                            gate2_w + l * 768, nlng, nlnb,
                                            xln);
  }
  vq_kernel<<<128, 256, 0, stream>>>(nodes, codebook, (float*)d_out);
}

// Round 12
// 317.460 us; speedup vs baseline: 1.1087x; 1.0324x over previous
//
#include <hip/hip_runtime.h>
#include <math.h>

// VQVAE graph-transformer forward, fp32 throughout.
// B=4 N=128 DIM=256 HEADS=8 DH=64 EDGE=64 DEPTH=2 K=512 INNER=512
// R20 = R17 (319us; attn = R13 i-quad shape — R18 occupancy and R19
// head-pair variants both regressed, attn optimum confirmed) + vq_fused:
// gate2(l1) folded into the VQ kernel as a prologue. Unlike the failed R15
// ff1/qkv prologue fusions (32x/24x redundant recompute), VQ blocks own
// their 4 rows exclusively -> gate computed exactly once per row; deletes
// the final gate_ln dispatch. vq_fused math harness-verified in R16.
// 13 dispatches.

#define DEV __device__ __forceinline__

constexpr int Bn = 4, Nn = 128, DIMn = 256, HEADSn = 8, DHn = 64, EDGEn = 64,
              DEPTHn = 2, Kn = 512, INNERn = 512;
constexpr int QKVW = 1536;
constexpr int PART = 131072;  // stride of partial buffers (floats)

DEV float wave_reduce_sum(float v) {
#pragma unroll
  for (int m = 32; m >= 1; m >>= 1) v += __shfl_xor(v, m);
  return v;
}

DEV float block_reduce_sum_256(float v, float* red) {
  v = wave_reduce_sum(v);
  int tid = threadIdx.x;
  if ((tid & 63) == 0) red[tid >> 6] = v;
  __syncthreads();
  v = red[0] + red[1] + red[2] + red[3];
  __syncthreads();
  return v;
}

DEV float gelu_exact(float x) {
  return 0.5f * x * (1.f + erff(x * 0.70710678118654752f));
}

// ---------------------------------------------------------------------------
// prep_kernel: all one-shot setup, block-range dispatched. 256 threads.
//  blk 0..431   : qkv weight+bias fold (216/layer: by 0..7 = W rows,
//                 by==8 = b_exp pseudo-row) 32x64 tiles, K=512, reg-dbuf
//  blk 432..943 : edge LN (b,i): 256 threads, vals[32]/thread
//  blk 944..1007: wfold W2 tile (l,h,nt), d-tiled 2x32
//  blk 1008..1015: wfold b_out2 (l,nt)
//  blk 1016..1031: rope tables
//  blk 1032..1543: LN0 row (xln + nodes copy)
__global__ __launch_bounds__(256) void prep_kernel(
    const float* __restrict__ edges, const float* __restrict__ eg,
    const float* __restrict__ eb, float* __restrict__ e,
    float* __restrict__ eT, float* __restrict__ cost, float* __restrict__ sint,
    const float* __restrict__ nodes_in, const float* __restrict__ ln1_g,
    const float* __restrict__ ln1_b, float* __restrict__ xln,
    float* __restrict__ nodes, const float* __restrict__ wek,
    const float* __restrict__ w_out, const float* __restrict__ bek,
    const float* __restrict__ b_out, float* __restrict__ W2,
    float* __restrict__ b_out2, const float* __restrict__ w_exp,
    const float* __restrict__ b_exp, const float* __restrict__ w_q,
    const float* __restrict__ b_q, const float* __restrict__ w_kv,
    const float* __restrict__ b_kv, float* __restrict__ WqkvF,
    float* __restrict__ bqkvF) {
  __shared__ __align__(16) float smem[4736];  // 18.9 KB, aliased per role
  int blk = blockIdx.x;
  int tid = threadIdx.x;

  if (blk < 432) {  // ---- qkv weight+bias fold: 32x64 tile, K=512, dbuf ----
    int t = blk;  // 0..431
    int l = t / 216, r = t % 216;
    int by = r / 24, bx = r % 24;
    bool biasrow = (by == 8);
    float* As = smem;            // [32][34]
    float* Bs = smem + 32 * 34;  // [32][68]
    int n0 = bx * 64;
    const float* Aab = w_exp + (size_t)l * 256 * 512 + (size_t)(by * 32) * 512;
    const float* be = b_exp + l * 512;
    const float* Wb;
    int ldw;
    if (n0 < 512) {
      Wb = w_q + (size_t)l * 512 * 512 + n0;
      ldw = 512;
    } else {
      Wb = w_kv + (size_t)l * 512 * 1024 + (n0 - 512);
      ldw = 1024;
    }
    int arow = tid >> 3, acol = (tid & 7) << 2;
    int brow = tid >> 4, bcol = (tid & 15) << 2;
    int tx = tid & 15, ty = tid >> 4;
    auto lda = [&](int kpos) -> float4 {
      return biasrow ? *(const float4*)(be + kpos + acol)
                     : *(const float4*)(Aab + (size_t)arow * 512 + kpos + acol);
    };
    float4 a_nxt = lda(0);
    float4 b0_nxt = *(const float4*)(Wb + (size_t)brow * ldw + bcol);
    float4 b1_nxt = *(const float4*)(Wb + (size_t)(brow + 16) * ldw + bcol);
    float acc[2][4] = {};
    for (int k0 = 0; k0 < 512; k0 += 32) {
      As[(acol + 0) * 34 + arow] = a_nxt.x;
      As[(acol + 1) * 34 + arow] = a_nxt.y;
      As[(acol + 2) * 34 + arow] = a_nxt.z;
      As[(acol + 3) * 34 + arow] = a_nxt.w;
      *(float4*)&Bs[brow * 68 + bcol] = b0_nxt;
      *(float4*)&Bs[(brow + 16) * 68 + bcol] = b1_nxt;
      __syncthreads();
      int kn = k0 + 32;
      if (kn < 512) {
        a_nxt = lda(kn);
        b0_nxt = *(const float4*)(Wb + (size_t)(kn + brow) * ldw + bcol);
        b1_nxt = *(const float4*)(Wb + (size_t)(kn + brow + 16) * ldw + bcol);
      }
#pragma unroll
      for (int kk = 0; kk < 32; ++kk) {
        float2 av = *(const float2*)&As[kk * 34 + ty * 2];
        float4 bv = *(const float4*)&Bs[kk * 68 + tx * 4];
        acc[0][0] += av.x * bv.x;
        acc[0][1] += av.x * bv.y;
        acc[0][2] += av.x * bv.z;
        acc[0][3] += av.x * bv.w;
        acc[1][0] += av.y * bv.x;
        acc[1][1] += av.y * bv.y;
        acc[1][2] += av.y * bv.z;
        acc[1][3] += av.y * bv.w;
      }
      __syncthreads();
    }
    if (!biasrow) {
#pragma unroll
      for (int u = 0; u < 2; ++u) {
        int d = by * 32 + ty * 2 + u;
        float4 o = {acc[u][0], acc[u][1], acc[u][2], acc[u][3]};
        *(float4*)(WqkvF + (size_t)l * 256 * 1536 + (size_t)d * 1536 + n0 +
                   tx * 4) = o;
      }
    } else if (ty == 0) {
      // pseudo-row d==0 (u==0) holds the b_exp dot; add base q/kv bias.
#pragma unroll
      for (int w = 0; w < 4; ++w) {
        int n = n0 + tx * 4 + w;
        float bb = (n < 512) ? b_q[l * 512 + n] : b_kv[l * 1024 + (n - 512)];
        bqkvF[l * 1536 + n] = acc[0][w] + bb;
      }
    }
  } else if (blk < 944) {  // ---- edge LN: 256 threads, no spill ----
    float* ets = smem;          // [128][33] = 4224
    float* redS = smem + 4224;  // 256
    float* redQ = smem + 4480;  // 256
    int eidx = blk - 432;
    int i = eidx & 127, b = eidx >> 7;
    int j = tid & 127, half = tid >> 7;
    const float* src = edges + (size_t)b * EDGEn * Nn * Nn +
                       (size_t)(half * 32) * (Nn * Nn) + i * Nn + j;
    float vals[32];
    float s = 0.f, q = 0.f;
#pragma unroll
    for (int cc = 0; cc < 32; ++cc) {
      float x = src[(size_t)cc * (Nn * Nn)];
      vals[cc] = x;
      s += x;
      q += x * x;
    }
    redS[tid] = s;
    redQ[tid] = q;
    __syncthreads();
    float ts = redS[j] + redS[j + 128];
    float tq = redQ[j] + redQ[j + 128];
    float m = ts * (1.0f / 64.0f);
    float var = tq * (1.0f / 64.0f) - m * m;
    float inv = 1.f / sqrtf(var + 1e-5f);
    float* dst = e + ((size_t)(b * Nn + i) * EDGEn) * Nn + j;
#pragma unroll
    for (int cc = 0; cc < 32; ++cc) {
      int c = half * 32 + cc;
      float o = (vals[cc] - m) * inv * eg[c] + eb[c];
      vals[cc] = o;
      dst[(size_t)c * Nn] = o;
    }
    float* dstT = eT + ((size_t)(b * Nn + i) * Nn) * EDGEn;
#pragma unroll
    for (int ch = 0; ch < 2; ++ch) {
      __syncthreads();  // guard ets reuse (and redS/redQ reads on pass 0)
      if (half == ch) {
#pragma unroll
        for (int cc = 0; cc < 32; ++cc) ets[j * 33 + cc] = vals[cc];
      }
      __syncthreads();
#pragma unroll
      for (int it = 0; it < 4; ++it) {
        int f4 = it * 256 + tid;  // 1024 float4s: 128 j x 8 c4
        int jj = f4 >> 3, c4 = (f4 & 7) << 2;
        float4 o4 = {ets[jj * 33 + c4], ets[jj * 33 + c4 + 1],
                     ets[jj * 33 + c4 + 2], ets[jj * 33 + c4 + 3]};
        *(float4*)(dstT + (size_t)jj * EDGEn + ch * 32 + c4) = o4;
      }
    }
  } else if (blk < 1008) {  // ---- wfold W2, d-tiled 2x32 ----
    int t = blk - 944;
    int l = t >> 5, h = (t >> 2) & 7, nt = t & 3;
    float* As = smem;            // [64][36] = 2304
    float* Bs = smem + 2304;     // [32][68] = 2176
    const float* wekl = wek + (size_t)l * 64 * 512 + h * 64;
    const float* woutl =
        w_out + (size_t)l * 512 * 256 + (size_t)(h * 64) * 256 + nt * 64;
    int tx = tid & 15, ty = tid >> 4;
    float acc[4][4] = {};
    for (int d0 = 0; d0 < 64; d0 += 32) {
      for (int f = tid; f < 512; f += 256) {
        int c = f >> 3, d4 = (f & 7) << 2;
        *(float4*)&As[c * 36 + d4] =
            *(const float4*)(wekl + (size_t)c * 512 + d0 + d4);
      }
      for (int f = tid; f < 512; f += 256) {
        int dd = f >> 4, n4 = (f & 15) << 2;
        *(float4*)&Bs[dd * 68 + n4] =
            *(const float4*)(woutl + (size_t)(d0 + dd) * 256 + n4);
      }
      __syncthreads();
#pragma unroll
      for (int dd = 0; dd < 32; ++dd) {
        float4 bv = *(const float4*)&Bs[dd * 68 + tx * 4];
#pragma unroll
        for (int u = 0; u < 4; ++u) {
          float a = As[(ty * 4 + u) * 36 + dd];
          acc[u][0] += a * bv.x;
          acc[u][1] += a * bv.y;
          acc[u][2] += a * bv.z;
          acc[u][3] += a * bv.w;
        }
      }
      __syncthreads();
    }
#pragma unroll
    for (int u = 0; u < 4; ++u) {
      float4 o = {acc[u][0], acc[u][1], acc[u][2], acc[u][3]};
      *(float4*)(W2 + (size_t)l * 512 * 256 +
                 (size_t)(h * 64 + ty * 4 + u) * 256 + nt * 64 + tx * 4) = o;
    }
  } else if (blk < 1016) {  // ---- wfold b_out2 ----
    int t = blk - 1008;
    int l = t >> 2, nt = t & 3;
    float* part = smem;
    int nn = tid & 63, kq = tid >> 6;
    const float* wcol = w_out + (size_t)l * 512 * 256 + nt * 64 + nn;
    float acc = 0.f;
    for (int k = kq * 128; k < kq * 128 + 128; ++k)
      acc += bek[l * 512 + k] * wcol[(size_t)k * 256];
    part[tid] = acc;
    __syncthreads();
    if (tid < 64)
      b_out2[l * 256 + nt * 64 + nn] =
          b_out[l * 256 + nt * 64 + nn] + part[nn] + part[64 + nn] +
          part[128 + nn] + part[192 + nn];
  } else if (blk < 1032) {  // ---- rope tables ----
    int t = (blk - 1016) * 256 + tid;
    if (t < Nn * 32) {
      int n = t >> 5, p = t & 31;
      float inv = powf(10000.f, -(float)(2 * p) / 64.f);
      float fr = (float)n * inv;
      cost[t] = cosf(fr);
      sint[t] = sinf(fr);
    }
  } else {  // ---- LN0 + nodes copy ----
    float* red = smem;
    int row = blk - 1032;
    float v = nodes_in[(size_t)row * DIMn + tid];
    nodes[(size_t)row * DIMn + tid] = v;
    float m = block_reduce_sum_256(v, red) * (1.0f / 256.0f);
    float d = v - m;
    float var = block_reduce_sum_256(d * d, red) * (1.0f / 256.0f);
    float inv = 1.f / sqrtf(var + 1e-5f);
    xln[(size_t)row * DIMn + tid] = d * inv * ln1_g[tid] + ln1_b[tid];
  }
}

// ---------------------------------------------------------------------------
// fp32 GEMM, 32x64 tile, BK=32, 2x4 microtile, register double-buffered.
// A2: A-stage sums two partials; aact==1: gelu after the sum.
// Dual-N (W2n at col>=N1), dual-K (k>=Ksplit reads Wkb), split-K via z.
// act: 0 none, 1 exact gelu, 4 qkv mode (rope cols<1024; k section -> kT).
__global__ __launch_bounds__(256) void gemm_kernel(
    const float* __restrict__ A, const float* __restrict__ A2, int aact,
    const float* __restrict__ W1, int N1, const float* __restrict__ b1,
    const float* __restrict__ W2n, int N2, const float* __restrict__ b2,
    const float* __restrict__ Wkb, int Ksplit, float* __restrict__ C, int M,
    int Ntot, int K, int kspan, int act, const float* __restrict__ cost,
    const float* __restrict__ sint, float* __restrict__ kT) {
  __shared__ float As[32][34];
  __shared__ __align__(16) float Bs[32][68];
  int tid = threadIdx.x;
  int bx = blockIdx.x, by = blockIdx.y, zid = blockIdx.z;
  int tx = tid & 15, ty = tid >> 4;
  int arow = tid >> 3, acol = (tid & 7) << 2;
  int brow = tid >> 4, bcol = (tid & 15) << 2;
  int col0 = bx * 64;
  const float* W = W1;
  const float* bias = b1;
  int Nw = N1, wcol = col0;
  if (W2n && col0 >= N1) {
    W = W2n;
    bias = b2;
    Nw = N2;
    wcol = col0 - N1;
  }
  int kb = zid * kspan, kend = kb + kspan;
  const float* arp = A + (size_t)(by * 32 + arow) * K;
  const float* arp2 = A2 ? A2 + (size_t)(by * 32 + arow) * K : nullptr;

  auto load_a = [&](int kpos) -> float4 {
    float4 a = *(const float4*)(arp + kpos + acol);
    if (arp2) {
      float4 a2 = *(const float4*)(arp2 + kpos + acol);
      a.x += a2.x;
      a.y += a2.y;
      a.z += a2.z;
      a.w += a2.w;
    }
    if (aact == 1) {
      a.x = gelu_exact(a.x);
      a.y = gelu_exact(a.y);
      a.z = gelu_exact(a.z);
      a.w = gelu_exact(a.w);
    }
    return a;
  };

  float4 a_nxt = load_a(kb);
  const float* w0p;
  const float* w1p;
  {
    int kr0 = kb + brow, kr1 = kb + brow + 16;
    w0p = (Ksplit && kr0 >= Ksplit)
              ? Wkb + (size_t)(kr0 - Ksplit) * Nw + wcol + bcol
              : W + (size_t)kr0 * Nw + wcol + bcol;
    w1p = (Ksplit && kr1 >= Ksplit)
              ? Wkb + (size_t)(kr1 - Ksplit) * Nw + wcol + bcol
              : W + (size_t)kr1 * Nw + wcol + bcol;
  }
  float4 b0_nxt = *(const float4*)w0p;
  float4 b1_nxt = *(const float4*)w1p;

  float acc[2][4] = {};
  for (int k0 = kb; k0 < kend; k0 += 32) {
    As[acol + 0][arow] = a_nxt.x;
    As[acol + 1][arow] = a_nxt.y;
    As[acol + 2][arow] = a_nxt.z;
    As[acol + 3][arow] = a_nxt.w;
    *(float4*)&Bs[brow][bcol] = b0_nxt;
    *(float4*)&Bs[brow + 16][bcol] = b1_nxt;
    __syncthreads();
    int kn = k0 + 32;
    if (kn < kend) {
      a_nxt = load_a(kn);
      int kr0 = kn + brow, kr1 = kn + brow + 16;
      w0p = (Ksplit && kr0 >= Ksplit)
                ? Wkb + (size_t)(kr0 - Ksplit) * Nw + wcol + bcol
                : W + (size_t)kr0 * Nw + wcol + bcol;
      w1p = (Ksplit && kr1 >= Ksplit)
                ? Wkb + (size_t)(kr1 - Ksplit) * Nw + wcol + bcol
                : W + (size_t)kr1 * Nw + wcol + bcol;
      b0_nxt = *(const float4*)w0p;
      b1_nxt = *(const float4*)w1p;
    }
#pragma unroll
    for (int kk = 0; kk < 32; ++kk) {
      float2 av = *(const float2*)&As[kk][ty * 2];
      float4 bv = *(const float4*)&Bs[kk][tx * 4];
      acc[0][0] += av.x * bv.x;
      acc[0][1] += av.x * bv.y;
      acc[0][2] += av.x * bv.z;
      acc[0][3] += av.x * bv.w;
      acc[1][0] += av.y * bv.x;
      acc[1][1] += av.y * bv.y;
      acc[1][2] += av.y * bv.z;
      acc[1][3] += av.y * bv.w;
    }
    __syncthreads();
  }
  int ccol = wcol + tx * 4;
  bool ksec = (act == 4) && (col0 >= 512) && (col0 < 1024);
  float* trans = (float*)Bs;
  float* Cz = C + (size_t)zid * M * Ntot;
#pragma unroll
  for (int u = 0; u < 2; ++u) {
    int r = by * 32 + ty * 2 + u;
    float o[4];
#pragma unroll
    for (int w = 0; w < 4; ++w)
      o[w] = acc[u][w] + (zid == 0 ? bias[ccol + w] : 0.f);
    if (act == 1) {
#pragma unroll
      for (int w = 0; w < 4; ++w) o[w] = gelu_exact(o[w]);
    } else if (act == 4 && col0 < 1024) {
      int n = r & 127;
      int p0 = (ccol & 63) >> 1;
      float c0 = cost[n * 32 + p0], s0 = sint[n * 32 + p0];
      float c1 = cost[n * 32 + p0 + 1], s1 = sint[n * 32 + p0 + 1];
      float x0 = o[0], x1 = o[1], x2 = o[2], x3 = o[3];
      o[0] = x0 * c0 - x1 * s0;
      o[1] = x1 * c0 + x0 * s0;
      o[2] = x2 * c1 - x3 * s1;
      o[3] = x3 * c1 + x2 * s1;
    }
    if (ksec) {
#pragma unroll
      for (int w = 0; w < 4; ++w) trans[(tx * 4 + w) * 33 + ty * 2 + u] = o[w];
    } else {
      float4 o4 = {o[0], o[1], o[2], o[3]};
      *(float4*)(Cz + (size_t)r * Ntot + col0 + tx * 4) = o4;
    }
  }
  if (ksec) {
    __syncthreads();
    int h = (col0 - 512) >> 6;
    int bb = (by * 32) >> 7;
#pragma unroll
    for (int q = 0; q < 2; ++q) {
      int f4 = tid * 2 + q;
      int dl = f4 >> 3, j4 = (f4 & 7) << 2;
      int jj = (by * 32 + j4) & 127;
      float4 o4 = {trans[dl * 33 + j4], trans[dl * 33 + j4 + 1],
                   trans[dl * 33 + j4 + 2], trans[dl * 33 + j4 + 3]};
      *(float4*)(kT + ((size_t)(bb * 8 + h) * 64 + dl) * 128 + jj) = o4;
    }
  }
}

// ---------------------------------------------------------------------------
// Attention + qe + out-proj partial. Block per (b,h,i-quad), 128 threads.
// Writes per-head proj partial: proj[h*PART + row*256 + n]. (R13 shape.)
__global__ __launch_bounds__(128) void attn_kernel(
    const float* __restrict__ qkv, const float* __restrict__ e,
    const float* __restrict__ eT, const float* __restrict__ kT,
    const float* __restrict__ wek, const float* __restrict__ w_out,
    const float* __restrict__ W2, float* __restrict__ proj) {
  __shared__ __align__(16) float qs[256];
  __shared__ __align__(16) float qes[256];
  __shared__ __align__(16) float att[512];
  __shared__ float avh[512];
  __shared__ float aeh[512];
  __shared__ float wekh[64 * 65];
  int blk = blockIdx.x;
  int iq = blk & 31;
  int bh = blk >> 5;
  int h = bh & 7, b = bh >> 3;
  int i0 = iq * 4;
  int row0 = b * 128 + i0;
  int tid = threadIdx.x;

  for (int f = tid; f < 256; f += 128) {
    int ii = f >> 6, d = f & 63;
    qs[f] = qkv[(size_t)(row0 + ii) * QKVW + h * 64 + d];
  }
  for (int f = tid; f < 4096; f += 128) {
    int c = f >> 6, d = f & 63;
    wekh[c * 65 + d] = wek[(size_t)c * INNERn + h * 64 + d];
  }
  __syncthreads();

  for (int f = tid; f < 256; f += 128) {
    int ii = f >> 6, c = f & 63;
    float acc = 0.f;
#pragma unroll
    for (int d = 0; d < 64; ++d) acc += qs[ii * 64 + d] * wekh[c * 65 + d];
    qes[f] = acc;
  }
  __syncthreads();

  int i2 = tid >> 5, j4 = tid & 31;
  float s0 = 0.f, s1 = 0.f, s2 = 0.f, s3 = 0.f;
  {
    const float* ktb = kT + ((size_t)bh * 64) * 128 + j4 * 4;
#pragma unroll
    for (int d4 = 0; d4 < 64; d4 += 4) {
      float4 q4 = *(const float4*)&qs[i2 * 64 + d4];
      float4 k0 = *(const float4*)(ktb + (size_t)(d4 + 0) * 128);
      float4 k1 = *(const float4*)(ktb + (size_t)(d4 + 1) * 128);
      float4 k2 = *(const float4*)(ktb + (size_t)(d4 + 2) * 128);
      float4 k3 = *(const float4*)(ktb + (size_t)(d4 + 3) * 128);
      s0 += q4.x * k0.x + q4.y * k1.x + q4.z * k2.x + q4.w * k3.x;
      s1 += q4.x * k0.y + q4.y * k1.y + q4.z * k2.y + q4.w * k3.y;
      s2 += q4.x * k0.z + q4.y * k1.z + q4.z * k2.z + q4.w * k3.z;
      s3 += q4.x * k0.w + q4.y * k1.w + q4.z * k2.w + q4.w * k3.w;
    }
    const float* eb = e + ((size_t)(row0 + i2) * 64) * 128 + j4 * 4;
#pragma unroll
    for (int c4 = 0; c4 < 64; c4 += 4) {
      float4 qe4 = *(const float4*)&qes[i2 * 64 + c4];
      float4 e0 = *(const float4*)(eb + (size_t)(c4 + 0) * 128);
      float4 e1 = *(const float4*)(eb + (size_t)(c4 + 1) * 128);
      float4 e2 = *(const float4*)(eb + (size_t)(c4 + 2) * 128);
      float4 e3 = *(const float4*)(eb + (size_t)(c4 + 3) * 128);
      s0 += qe4.x * e0.x + qe4.y * e1.x + qe4.z * e2.x + qe4.w * e3.x;
      s1 += qe4.x * e0.y + qe4.y * e1.y + qe4.z * e2.y + qe4.w * e3.y;
      s2 += qe4.x * e0.z + qe4.y * e1.z + qe4.z * e2.z + qe4.w * e3.z;
      s3 += qe4.x * e0.w + qe4.y * e1.w + qe4.z * e2.w + qe4.w * e3.w;
    }
    s0 *= 0.125f;
    s1 *= 0.125f;
    s2 *= 0.125f;
    s3 *= 0.125f;
  }
  {
    float mx = fmaxf(fmaxf(s0, s1), fmaxf(s2, s3));
#pragma unroll
    for (int m = 16; m >= 1; m >>= 1) mx = fmaxf(mx, __shfl_xor(mx, m));
    float p0 = expf(s0 - mx), p1 = expf(s1 - mx), p2 = expf(s2 - mx),
          p3 = expf(s3 - mx);
    float sm = p0 + p1 + p2 + p3;
#pragma unroll
    for (int m = 16; m >= 1; m >>= 1) sm += __shfl_xor(sm, m);
    float inv = 1.f / sm;
    float4 a4 = {p0 * inv, p1 * inv, p2 * inv, p3 * inv};
    *(float4*)&att[i2 * 128 + j4 * 4] = a4;
  }
  __syncthreads();

  {
    int d = tid & 63, half = tid >> 6;
    float av0 = 0.f, av1 = 0.f, av2 = 0.f, av3 = 0.f;
    float ae0 = 0.f, ae1 = 0.f, ae2 = 0.f, ae3 = 0.f;
    const float* vb = qkv + (size_t)(b * 128) * QKVW + 1024 + h * 64 + d;
    const float* etb = eT + ((size_t)row0 * 128) * 64 + d;
    for (int jq = 0; jq < 16; ++jq) {
      int jb = half * 64 + jq * 4;
      float4 a0 = *(const float4*)&att[0 * 128 + jb];
      float4 a1 = *(const float4*)&att[1 * 128 + jb];
      float4 a2 = *(const float4*)&att[2 * 128 + jb];
      float4 a3 = *(const float4*)&att[3 * 128 + jb];
#pragma unroll
      for (int t = 0; t < 4; ++t) {
        int j = jb + t;
        float vv = vb[(size_t)j * QKVW];
        float at0 = ((const float*)&a0)[t];
        float at1 = ((const float*)&a1)[t];
        float at2 = ((const float*)&a2)[t];
        float at3 = ((const float*)&a3)[t];
        av0 += at0 * vv;
        av1 += at1 * vv;
        av2 += at2 * vv;
        av3 += at3 * vv;
        float e0 = etb[(size_t)j * 64];
        float e1 = etb[8192 + (size_t)j * 64];
        float e2 = etb[16384 + (size_t)j * 64];
        float e3 = etb[24576 + (size_t)j * 64];
        ae0 += at0 * e0;
        ae1 += at1 * e1;
        ae2 += at2 * e2;
        ae3 += at3 * e3;
      }
    }
    avh[half * 256 + 0 * 64 + d] = av0;
    avh[half * 256 + 1 * 64 + d] = av1;
    avh[half * 256 + 2 * 64 + d] = av2;
    avh[half * 256 + 3 * 64 + d] = av3;
    aeh[half * 256 + 0 * 64 + d] = ae0;
    aeh[half * 256 + 1 * 64 + d] = ae1;
    aeh[half * 256 + 2 * 64 + d] = ae2;
    aeh[half * 256 + 3 * 64 + d] = ae3;
  }
  __syncthreads();

  for (int f = tid; f < 256; f += 128) {
    int ii = f >> 6, dd = f & 63;
    att[ii * 128 + dd] = avh[ii * 64 + dd] + avh[256 + ii * 64 + dd];
    att[ii * 128 + 64 + dd] = aeh[ii * 64 + dd] + aeh[256 + ii * 64 + dd];
  }
  __syncthreads();

  {
    int rp = tid >> 6, n4 = (tid & 63) << 2;
    int r0 = rp * 2, r1 = rp * 2 + 1;
    float o0[4] = {}, o1[4] = {};
    const float* wo = w_out + (size_t)(h * 64) * 256 + n4;
#pragma unroll 8
    for (int k = 0; k < 64; ++k) {
      float4 w4 = *(const float4*)(wo + (size_t)k * 256);
      float a0 = att[r0 * 128 + k];
      float a1 = att[r1 * 128 + k];
      o0[0] += a0 * w4.x;
      o0[1] += a0 * w4.y;
      o0[2] += a0 * w4.z;
      o0[3] += a0 * w4.w;
      o1[0] += a1 * w4.x;
      o1[1] += a1 * w4.y;
      o1[2] += a1 * w4.z;
      o1[3] += a1 * w4.w;
    }
    const float* w2 = W2 + (size_t)(h * 64) * 256 + n4;
#pragma unroll 8
    for (int k = 0; k < 64; ++k) {
      float4 w4 = *(const float4*)(w2 + (size_t)k * 256);
      float a0 = att[r0 * 128 + 64 + k];
      float a1 = att[r1 * 128 + 64 + k];
      o0[0] += a0 * w4.x;
      o0[1] += a0 * w4.y;
      o0[2] += a0 * w4.z;
      o0[3] += a0 * w4.w;
      o1[0] += a1 * w4.x;
      o1[1] += a1 * w4.y;
      o1[2] += a1 * w4.z;
      o1[3] += a1 * w4.w;
    }
    float* pp = proj + (size_t)h * PART;
    float4 v0 = {o0[0], o0[1], o0[2], o0[3]};
    float4 v1 = {o1[0], o1[1], o1[2], o1[3]};
    *(float4*)(pp + (size_t)(row0 + r0) * 256 + n4) = v0;
    *(float4*)(pp + (size_t)(row0 + r1) * 256 + n4) = v1;
  }
}

// ---------------------------------------------------------------------------
// Gated residual + optional fused LN. x = sum of nparts partials (+ badd).
__global__ __launch_bounds__(256) void gate_ln_kernel(
    const float* __restrict__ x, int nparts, const float* __restrict__ badd,
    float* __restrict__ nodes, const float* __restrict__ gw,
    const float* __restrict__ lng, const float* __restrict__ lnb,
    float* __restrict__ xln) {
  __shared__ float red[4];
  int row = blockIdx.x, tid = threadIdx.x;
  size_t off = (size_t)row * DIMn + tid;
  float xv = x[off];
  for (int p = 1; p < nparts; ++p) xv += x[off + (size_t)p * PART];
  if (badd) xv += badd[tid];
  float rv = nodes[off];
  float pv =
      xv * gw[tid] + rv * gw[DIMn + tid] + (xv - rv) * gw[2 * DIMn + tid];
  float ssum = block_reduce_sum_256(pv, red);
  float gsig = 1.f / (1.f + expf(-ssum));
  float nv = xv * gsig + rv * (1.f - gsig);
  nodes[off] = nv;
  if (lng) {
    float m = block_reduce_sum_256(nv, red) * (1.0f / 256.0f);
    float d = nv - m;
    float var = block_reduce_sum_256(d * d, red) * (1.0f / 256.0f);
    float inv = 1.f / sqrtf(var + 1e-5f);
    xln[off] = d * inv * lng[tid] + lnb[tid];
  }
}

// ---------------------------------------------------------------------------
// VQ nearest neighbor with fused gate2(l1) prologue: zs = gate2(4 ff2
// partials, nodesRes) for this block's 4 rows (wave-per-row, gate only).
// Each row owned by exactly one block -> no redundant recompute.
__global__ __launch_bounds__(256) void vq_fused_kernel(
    const float* __restrict__ parts, const float* __restrict__ nodesRes,
    const float* __restrict__ gw, const float* __restrict__ codebook,
    float* __restrict__ out) {
  __shared__ __align__(16) float zs[4 * 256];
  __shared__ float wval[4][4];
  __shared__ int widx[4][4];
  __shared__ int fidx[4];
  int row0 = blockIdx.x * 4;
  int tid = threadIdx.x;
  {
    int wv = tid >> 6, lane = tid & 63;
    int row = row0 + wv;
    float xv[4], rv[4];
    float pv = 0.f;
#pragma unroll
    for (int cq = 0; cq < 4; ++cq) {
      int c = lane + cq * 64;
      float x = 0.f;
#pragma unroll
      for (int p = 0; p < 4; ++p)
        x += parts[(size_t)p * PART + (size_t)row * 256 + c];
      float rvv = nodesRes[(size_t)row * 256 + c];
      xv[cq] = x;
      rv[cq] = rvv;
      pv += x * gw[c] + rvv * gw[256 + c] + (x - rvv) * gw[512 + c];
    }
    float ssum = wave_reduce_sum(pv);
    float gsig = 1.f / (1.f + expf(-ssum));
#pragma unroll
    for (int cq = 0; cq < 4; ++cq) {
      int c = lane + cq * 64;
      zs[wv * 256 + c] = xv[cq] * gsig + rv[cq] * (1.f - gsig);
    }
  }
  __syncthreads();
  int k1 = tid, k2 = tid + 256;
  const float4* c1p = (const float4*)(codebook + (size_t)k1 * DIMn);
  const float4* c2p = (const float4*)(codebook + (size_t)k2 * DIMn);
  float dot[4][2] = {};
  float cc0 = 0.f, cc1 = 0.f;
#pragma unroll 8
  for (int d4 = 0; d4 < 64; ++d4) {
    float4 c1 = c1p[d4], c2 = c2p[d4];
    cc0 += c1.x * c1.x + c1.y * c1.y + c1.z * c1.z + c1.w * c1.w;
    cc1 += c2.x * c2.x + c2.y * c2.y + c2.z * c2.z + c2.w * c2.w;
#pragma unroll
    for (int r = 0; r < 4; ++r) {
      float4 z = *(const float4*)&zs[r * 256 + d4 * 4];
      dot[r][0] += c1.x * z.x + c1.y * z.y + c1.z * z.z + c1.w * z.w;
      dot[r][1] += c2.x * z.x + c2.y * z.y + c2.z * z.z + c2.w * z.w;
    }
  }
  int lane = tid & 63, w = tid >> 6;
#pragma unroll
  for (int r = 0; r < 4; ++r) {
    float bv = cc0 - 2.f * dot[r][0];
    int bi = k1;
    float v2 = cc1 - 2.f * dot[r][1];
    if (v2 < bv) {
      bv = v2;
      bi = k2;
    }
#pragma unroll
    for (int m = 32; m >= 1; m >>= 1) {
      float ov = __shfl_xor(bv, m);
      int oi = __shfl_xor(bi, m);
      if (ov < bv || (ov == bv && oi < bi)) {
        bv = ov;
        bi = oi;
      }
    }
    if (lane == 0) {
      wval[r][w] = bv;
      widx[r][w] = bi;
    }
  }
  __syncthreads();
  if (tid < 4) {
    float bb = wval[tid][0];
    int bi = widx[tid][0];
    for (int t = 1; t < 4; ++t)
      if (wval[tid][t] < bb || (wval[tid][t] == bb && widx[tid][t] < bi)) {
        bb = wval[tid][t];
        bi = widx[tid][t];
      }
    fidx[tid] = bi;
  }
  __syncthreads();
  for (int f = tid; f < 1024; f += 256) {
    int r = f >> 8, d = f & 255;
    float zv = zs[f];
    float zq = codebook[(size_t)fidx[r] * DIMn + d];
    out[(size_t)(row0 + r) * DIMn + d] = zv + (zq - zv);
  }
}

// ---------------------------------------------------------------------------
extern "C" void kernel_launch(void* const* d_in, const int* in_sizes, int n_in,
                              void* d_out, int out_size, void* d_ws,
                              size_t ws_size, hipStream_t stream) {
  const float* nodes_in = (const float*)d_in[0];
  const float* edges = (const float*)d_in[1];
  const float* edge_ln_g = (const float*)d_in[2];
  const float* edge_ln_b = (const float*)d_in[3];
  const float* ln1_g = (const float*)d_in[4];
  const float* ln1_b = (const float*)d_in[5];
  const float* w_exp = (const float*)d_in[6];
  const float* b_exp = (const float*)d_in[7];
  const float* w_q = (const float*)d_in[8];
  const float* b_q = (const float*)d_in[9];
  const float* w_kv = (const float*)d_in[10];
  const float* b_kv = (const float*)d_in[11];
  const float* w_ekv = (const float*)d_in[12];
  const float* b_ekv = (const float*)d_in[13];
  const float* w_out = (const float*)d_in[14];
  const float* b_out = (const float*)d_in[15];
  const float* gate1_w = (const float*)d_in[16];
  const float* ln2_g = (const float*)d_in[17];
  const float* ln2_b = (const float*)d_in[18];
  const float* w_ff1 = (const float*)d_in[19];
  const float* b_ff1 = (const float*)d_in[20];
  const float* w_ff2 = (const float*)d_in[21];
  const float* b_ff2 = (const float*)d_in[22];
  const float* gate2_w = (const float*)d_in[23];
  const float* codebook = (const float*)d_in[24];

  float* ws = (float*)d_ws;
  float* e_buf = ws;                  // 4194304
  float* eT_buf = e_buf + 4194304;    // 4194304
  float* cost = eT_buf + 4194304;     // 4096
  float* sint = cost + 4096;          // 4096
  float* nodes = sint + 4096;         // 131072
  float* xln = nodes + 131072;        // 131072
  float* qkvb = xln + 131072;         // 786432
  float* kTb = qkvb + 786432;         // 262144
  float* proj = kTb + 262144;         // 1048576 (8 per-head / 4 splitK parts)
  float* ff1 = proj + 1048576;        // 1048576 (2 split-K partials)
  float* W2buf = ff1 + 1048576;       // 262144
  float* bout2 = W2buf + 262144;      // 512
  float* WqkvF = bout2 + 512;         // 786432 (2 layers x 256 x 1536)
  float* bqkvF = WqkvF + 786432;      // 3072

  // one-shot setup: fold (weight+bias) first, edge LN, W2, rope, LN0 fillers
  prep_kernel<<<1544, 256, 0, stream>>>(
      edges, edge_ln_g, edge_ln_b, e_buf, eT_buf, cost, sint, nodes_in, ln1_g,
      ln1_b, xln, nodes, w_ekv, w_out, b_ekv, b_out, W2buf, bout2, w_exp,
      b_exp, w_q, b_q, w_kv, b_kv, WqkvF, bqkvF);

  for (int l = 0; l < DEPTHn; ++l) {
    // fused q|kv directly from xln via folded weights (K=256), rope + kT
    gemm_kernel<<<dim3(24, 16, 1), 256, 0, stream>>>(
        xln, nullptr, 0, WqkvF + (size_t)l * 256 * 1536, 1536,
        bqkvF + l * 1536, nullptr, 0, nullptr, nullptr, 0, qkvb, 512, QKVW,
        256, 256, 4, cost, sint, kTb);
    // attention (+qe, +out-proj per-head partials)
    attn_kernel<<<1024, 128, 0, stream>>>(qkvb, e_buf, eT_buf, kTb,
                                          w_ekv + l * 64 * 512,
                                          w_out + l * 512 * 256,
                                          W2buf + l * 512 * 256, proj);
    gate_ln_kernel<<<512, 256, 0, stream>>>(
        proj, 8, bout2 + l * 256, nodes, gate1_w + l * 768, ln2_g + l * 256,
        ln2_b + l * 256, xln);
    // ff1: split-K x2 (gelu deferred to ff2 A-stage)
    gemm_kernel<<<dim3(16, 16, 2), 256, 0, stream>>>(
        xln, nullptr, 0, w_ff1 + l * 256 * 1024, 1024, b_ff1 + l * 1024,
        nullptr, 0, nullptr, nullptr, 0, ff1, 512, 1024, 256, 128, 0, cost,
        sint, nullptr);
    // ff2: A = gelu(ff1 p0 + p1), split-K x4 -> proj partials
    gemm_kernel<<<dim3(4, 16, 4), 256, 0, stream>>>(
        ff1, ff1 + 524288, 1, w_ff2 + l * 1024 * 256, 256, b_ff2 + l * 256,
        nullptr, 0, nullptr, nullptr, 0, proj, 512, 256, 1024, 256, 0, cost,
        sint, nullptr);
    if (l + 1 < DEPTHn) {
      // gate2(l0) + LN1(l1) -> xln for next layer's qkv
      gate_ln_kernel<<<512, 256, 0, stream>>>(proj, 4, nullptr, nodes,
                                              gate2_w + l * 768,
                                              ln1_g + (l + 1) * 256,
                                              ln1_b + (l + 1) * 256, xln);
    }
  }
  // VQ with fused gate2(l1) prologue (each row owned by one block)
  vq_fused_kernel<<<128, 256, 0, stream>>>(proj, nodes, gate2_w + 768,
                                           codebook, (float*)d_out);
}